// Round 9
// baseline (899.956 us; speedup 1.0000x reference)
//
#include <hip/hip_runtime.h>
#include <hip/hip_bf16.h>

typedef __hip_bfloat16 bf16;
typedef __bf16 bf16x8 __attribute__((ext_vector_type(8)));
typedef float f32x4 __attribute__((ext_vector_type(4)));

static constexpr int cB = 200, cN = 384, cM = 512, cH = 128;
static constexpr int cNN  = cB * cN;     // 76800
static constexpr int cE   = 2 * cB * cM; // 204800 edges
static constexpr int cTWOM = 2 * cM;     // 1024
static constexpr int ZROW = 2 * cM + cN; // 1408
static constexpr int CROW = cM + 2 * cN; // 1280
static constexpr int ZBASE = cB * ZROW;  // 281600

__device__ __forceinline__ float b2f(bf16 x) { return __bfloat162float(x); }
__device__ __forceinline__ bf16  f2b(float x) { return __float2bfloat16(x); }

// ---------------- normalize edge_index / numSwitches (int32 or int64 low words) ----
__global__ __launch_bounds__(256) void k_norm_idx(const int* __restrict__ ei_raw,
                                                  const int* __restrict__ nsw_raw,
                                                  int* __restrict__ ei, int* __restrict__ nsw) {
  int z = 0;
#pragma unroll
  for (int j = 1; j < 64; j += 2) z |= ei_raw[j];
  const int f = (z == 0) ? 1 : 0;
  const int i = blockIdx.x * 256 + threadIdx.x;
  if (i < 2 * cE) ei[i] = ei_raw[i << f];
  if (blockIdx.x == 0 && threadIdx.x < cB) nsw[threadIdx.x] = nsw_raw[threadIdx.x << f];
}

__global__ __launch_bounds__(256) void k_fill(float* p, float v, int count) {
  int i = blockIdx.x * 256 + threadIdx.x;
  if (i < count) p[i] = v;
}

__global__ __launch_bounds__(256) void k_deg(const int* __restrict__ ei, float* deg) {
  int e = blockIdx.x * 256 + threadIdx.x;
  if (e < cE) atomicAdd(&deg[ei[cE + e]], 1.0f);
}

__global__ __launch_bounds__(256) void k_dinv(float* deg) {
  int i = blockIdx.x * 256 + threadIdx.x;
  if (i < cNN) deg[i] = rsqrtf(deg[i]);
}

// ---------------- layer 1 linear: hraw = x@W1 + b1 ----------------
__global__ __launch_bounds__(256) void k_lin1(const float* __restrict__ x, const float* __restrict__ W1,
                                              const float* __restrict__ b1, bf16* __restrict__ hraw) {
  int idx = blockIdx.x * 256 + threadIdx.x;
  if (idx >= cNN * cH) return;
  int n = idx >> 7, h = idx & 127;
  hraw[idx] = f2b(x[2 * n] * W1[h] + x[2 * n + 1] * W1[cH + h] + b1[h]);
}

// ---------------- LDS-accumulated edge scatter ----------------
// block = (batch b, feature-quarter). Batch b owns edges [b*1024, b*1024+1024).
__global__ __launch_bounds__(256) void k_scat_lds(const int* __restrict__ ei, const bf16* __restrict__ hsrc,
                                                  const float* __restrict__ dinv, float* __restrict__ agg) {
  constexpr int FQ = 32;
  __shared__ float acc[cN * FQ];   // 48 KB
  __shared__ float nrm[1024];      // 4 KB
  __shared__ int   srcn[1024];     // 4 KB
  __shared__ int   dstn[1024];     // 4 KB
  const int tid = threadIdx.x;
  const int b = blockIdx.x >> 2;
  const int f0 = (blockIdx.x & 3) * FQ;
  for (int i = tid; i < cN * FQ; i += 256) acc[i] = 0.f;
  for (int i = tid; i < 1024; i += 256) {
    const int e = b * cTWOM + i;        // per-batch contiguous edge slice
    const int s = ei[e], d = ei[cE + e];
    srcn[i] = s;
    dstn[i] = (d - b * cN) * FQ;
    nrm[i] = dinv[s] * dinv[d];
  }
  __syncthreads();
  const int f = tid & (FQ - 1);
  const int e0 = tid >> 5;               // 8 edges per 256-thread pass
  for (int ee = e0; ee < 1024; ee += 8) {
    const float v = b2f(hsrc[(size_t)srcn[ee] * cH + f0 + f]) * nrm[ee];
    atomicAdd(&acc[dstn[ee] + f], v);
  }
  __syncthreads();
  for (int i = tid; i < cN * FQ; i += 256) {
    const int n = i / FQ, ff = i - n * FQ;
    agg[((size_t)(b * cN + n)) * cH + f0 + ff] = acc[i];
  }
}

// ---------------- relu(agg + self) ----------------
__global__ __launch_bounds__(256) void k_reluagg(const float* __restrict__ agg, const bf16* __restrict__ hself,
                                                 const float* __restrict__ dinv, bf16* __restrict__ outh) {
  int idx = blockIdx.x * 256 + threadIdx.x;
  if (idx >= cNN * cH) return;
  int n = idx >> 7;
  float dn = dinv[n];
  float v = agg[idx] + b2f(hself[idx]) * dn * dn;
  outh[idx] = f2b(fmaxf(v, 0.0f));
}

// ---------------- layer 2 linear: h2raw = h1@W2 + b2 ----------------
__global__ __launch_bounds__(256) void k_lin2(const bf16* __restrict__ h1, const float* __restrict__ W2,
                                              const float* __restrict__ b2v, bf16* __restrict__ h2raw) {
  __shared__ float w2s[64 * cH];
  __shared__ float ts[8][cH];
  const int tid = threadIdx.x;
  const int n0 = blockIdx.x * 8;
  for (int i = tid; i < 8 * cH; i += 256)
    ts[i >> 7][i & 127] = b2f(h1[(size_t)(n0 + (i >> 7)) * cH + (i & 127)]);
  const int hp = (tid & 63) * 2;
  const int ng = tid >> 6;
  const int e0 = ng, e1 = ng + 4;
  float a00 = 0, a01 = 0, a10 = 0, a11 = 0;
  for (int half = 0; half < 2; ++half) {
    __syncthreads();
    for (int i = tid; i < 64 * cH; i += 256) w2s[i] = W2[half * 64 * cH + i];
    __syncthreads();
    const int kb = half * 64;
#pragma unroll 8
    for (int k = 0; k < 64; ++k) {
      const float w0 = w2s[k * cH + hp];
      const float w1 = w2s[k * cH + hp + 1];
      const float t0 = ts[e0][kb + k];
      const float t1 = ts[e1][kb + k];
      a00 = fmaf(t0, w0, a00); a01 = fmaf(t0, w1, a01);
      a10 = fmaf(t1, w0, a10); a11 = fmaf(t1, w1, a11);
    }
  }
  h2raw[(size_t)(n0 + e0) * cH + hp]     = f2b(a00 + b2v[hp]);
  h2raw[(size_t)(n0 + e0) * cH + hp + 1] = f2b(a01 + b2v[hp + 1]);
  h2raw[(size_t)(n0 + e1) * cH + hp]     = f2b(a10 + b2v[hp]);
  h2raw[(size_t)(n0 + e1) * cH + hp + 1] = f2b(a11 + b2v[hp + 1]);
}

// ---------------- x_g = sum_n xg ----------------
__global__ __launch_bounds__(128) void k_xgsum(const bf16* __restrict__ xg, float* __restrict__ x_g) {
  int b = blockIdx.x, h = threadIdx.x;
  float s = 0.f;
  const bf16* p = xg + (size_t)b * cN * cH + h;
  for (int n = 0; n < cN; ++n) s += b2f(p[(size_t)n * cH]);
  x_g[b * cH + h] = s;
}

// ---------------- weight prep: transposes to bf16 + Wc2 pad to float4 ----------------
__global__ __launch_bounds__(256) void k_wt(const float* __restrict__ Ws1, const float* __restrict__ Wc1,
                                            const float* __restrict__ Wc2,
                                            bf16* __restrict__ Ws1t, bf16* __restrict__ Wc1t,
                                            float* __restrict__ Wc2p) {
  int idx = blockIdx.x * 256 + threadIdx.x;
  if (idx < 512 * 256) {
    int j = idx >> 8, k = idx & 255;
    Ws1t[idx] = f2b(Ws1[k * 512 + j]);
  }
  if (idx < 384 * 256) {
    int j = idx >> 8, k = idx & 255;
    Wc1t[idx] = f2b(Wc1[k * 384 + j]);
  }
  if (idx < 384 * 4) {
    int j = idx >> 2, o = idx & 3;
    Wc2p[idx] = (o < 3) ? Wc2[j * 3 + o] : 0.f;
  }
}

// ---------------- g_s = x_g@Ws1[256:]+bs1 ; g_c = x_g@Wc1[256:]+bc1 (exact, f32) ----------
__global__ __launch_bounds__(512) void k_gsgc(const float* __restrict__ x_g, const float* __restrict__ Ws1,
                                              const float* __restrict__ bs1, const float* __restrict__ Wc1,
                                              const float* __restrict__ bc1, float* __restrict__ g_s,
                                              float* __restrict__ g_c) {
  __shared__ float xs[cH];
  const int b = blockIdx.x, tid = threadIdx.x;
  if (tid < cH) xs[tid] = x_g[b * cH + tid];
  __syncthreads();
  {
    float acc = bs1[tid];
    for (int k = 0; k < cH; ++k) acc = fmaf(xs[k], Ws1[(2 * cH + k) * 512 + tid], acc);
    g_s[b * 512 + tid] = acc;
  }
  if (tid < 384) {
    float acc = bc1[tid];
    for (int k = 0; k < cH; ++k) acc = fmaf(xs[k], Wc1[(2 * cH + k) * 384 + tid], acc);
    g_c[b * 384 + tid] = acc;
  }
}

// ---------------- per-edge MLPs via MFMA: 32 edges/block, in-register 2nd layer ----------
__global__ __launch_bounds__(256) void k_mlp_mfma(
    const int* __restrict__ ei, const int* __restrict__ nsw, const bf16* __restrict__ xg,
    const bf16* __restrict__ Ws1t, const bf16* __restrict__ Wc1t,
    const float* __restrict__ g_s, const float* __restrict__ g_c,
    const float* __restrict__ Ws2, const float* __restrict__ bs2,
    const float* __restrict__ Wc2p, const float* __restrict__ bc2,
    float* __restrict__ gt_w, float* __restrict__ wvp_w, float* __restrict__ wvc_w,
    float* __restrict__ pfc_w, float* __restrict__ out) {
  constexpr int FS = 264;   // feat row stride (bf16)
  __shared__ __align__(16) bf16 feat[32 * FS];   // 16.5 KB
  __shared__ float gsl[512];                      // 2 KB
  __shared__ float gcl[384];                      // 1.5 KB
  __shared__ float red_s[4][32][4];               // 2 KB
  __shared__ float red_c[4][32][4];               // 2 KB

  const int tid = threadIdx.x;
  const int b = blockIdx.x >> 4;
  const int m0 = (blockIdx.x & 15) << 5;   // 32 edges per block
  const int wv = tid >> 6, ln = tid & 63;
  const int fr = ln & 15;
  const int g4 = ln >> 4;            // 0..3
  const int ak = g4 * 8;             // fragment k offset

  // ---- gather feat[e][0:256] = [xg[pn] | xg[cn]]; stage g vectors ----
  {
    const int e = tid >> 3, j = tid & 7;
    const int m = m0 + e;
    const int pn = ei[b * cTWOM + m];
    const int cn = ei[b * cTWOM + cM + m];
    const uint4* ps = (const uint4*)(xg + (size_t)pn * cH);
    const uint4* cs = (const uint4*)(xg + (size_t)cn * cH);
    uint4* fp = (uint4*)(feat + e * FS);
    uint4* fc = (uint4*)(feat + e * FS + 128);
    fp[2 * j]     = ps[2 * j];
    fp[2 * j + 1] = ps[2 * j + 1];
    fc[2 * j]     = cs[2 * j];
    fc[2 * j + 1] = cs[2 * j + 1];
  }
  for (int i = tid; i < 512; i += 256) gsl[i] = g_s[b * 512 + i];
  for (int i = tid; i < 384; i += 256) gcl[i] = g_c[b * 384 + i];
  __syncthreads();

  const bf16* ap = feat + fr * FS + ak;

  // ================= S path: cols wv*128 + nt*16 + fr =================
  {
    f32x4 acc[2][8];
#pragma unroll
    for (int m = 0; m < 2; ++m)
#pragma unroll
      for (int n = 0; n < 8; ++n) acc[m][n] = f32x4{0.f, 0.f, 0.f, 0.f};
    const bf16* bp = Ws1t + ((size_t)(wv * 128 + fr)) * 256 + ak;
#pragma unroll
    for (int kt = 0; kt < 8; ++kt) {
      const int ko = kt * 32;
      const bf16x8 a0 = *(const bf16x8*)(ap + ko);
      const bf16x8 a1 = *(const bf16x8*)(ap + 16 * FS + ko);
#pragma unroll
      for (int nt = 0; nt < 8; ++nt) {
        const bf16x8 bfr = *(const bf16x8*)(bp + nt * 16 * 256 + ko);
        acc[0][nt] = __builtin_amdgcn_mfma_f32_16x16x32_bf16(a0, bfr, acc[0][nt], 0, 0, 0);
        acc[1][nt] = __builtin_amdgcn_mfma_f32_16x16x32_bf16(a1, bfr, acc[1][nt], 0, 0, 0);
      }
    }
    // in-register second layer: p[m][i][o]
    float p[2][4][4];
#pragma unroll
    for (int m = 0; m < 2; ++m)
#pragma unroll
      for (int i = 0; i < 4; ++i)
#pragma unroll
        for (int o = 0; o < 4; ++o) p[m][i][o] = 0.f;
#pragma unroll
    for (int nt = 0; nt < 8; ++nt) {
      const int col = wv * 128 + nt * 16 + fr;
      const float4 w4 = *(const float4*)(Ws2 + col * 4);
      const float gs = gsl[col];
#pragma unroll
      for (int m = 0; m < 2; ++m)
#pragma unroll
        for (int i = 0; i < 4; ++i) {
          const float hv = fmaxf(acc[m][nt][i] + gs, 0.f);
          p[m][i][0] = fmaf(hv, w4.x, p[m][i][0]);
          p[m][i][1] = fmaf(hv, w4.y, p[m][i][1]);
          p[m][i][2] = fmaf(hv, w4.z, p[m][i][2]);
          p[m][i][3] = fmaf(hv, w4.w, p[m][i][3]);
        }
    }
#pragma unroll
    for (int mask = 1; mask <= 8; mask <<= 1)
#pragma unroll
      for (int m = 0; m < 2; ++m)
#pragma unroll
        for (int i = 0; i < 4; ++i)
#pragma unroll
          for (int o = 0; o < 4; ++o) p[m][i][o] += __shfl_xor(p[m][i][o], mask);
    if (fr == 0) {
#pragma unroll
      for (int m = 0; m < 2; ++m)
#pragma unroll
        for (int i = 0; i < 4; ++i) {
          const int row = m * 16 + g4 * 4 + i;
#pragma unroll
          for (int o = 0; o < 4; ++o) red_s[wv][row][o] = p[m][i][o];
        }
    }
  }

  // ================= C path: cols wv*96 + nt*16 + fr =================
  {
    f32x4 acc[2][6];
#pragma unroll
    for (int m = 0; m < 2; ++m)
#pragma unroll
      for (int n = 0; n < 6; ++n) acc[m][n] = f32x4{0.f, 0.f, 0.f, 0.f};
    const bf16* bp = Wc1t + ((size_t)(wv * 96 + fr)) * 256 + ak;
#pragma unroll
    for (int kt = 0; kt < 8; ++kt) {
      const int ko = kt * 32;
      const bf16x8 a0 = *(const bf16x8*)(ap + ko);
      const bf16x8 a1 = *(const bf16x8*)(ap + 16 * FS + ko);
#pragma unroll
      for (int nt = 0; nt < 6; ++nt) {
        const bf16x8 bfr = *(const bf16x8*)(bp + nt * 16 * 256 + ko);
        acc[0][nt] = __builtin_amdgcn_mfma_f32_16x16x32_bf16(a0, bfr, acc[0][nt], 0, 0, 0);
        acc[1][nt] = __builtin_amdgcn_mfma_f32_16x16x32_bf16(a1, bfr, acc[1][nt], 0, 0, 0);
      }
    }
    float p[2][4][4];
#pragma unroll
    for (int m = 0; m < 2; ++m)
#pragma unroll
      for (int i = 0; i < 4; ++i)
#pragma unroll
        for (int o = 0; o < 4; ++o) p[m][i][o] = 0.f;
#pragma unroll
    for (int nt = 0; nt < 6; ++nt) {
      const int col = wv * 96 + nt * 16 + fr;
      const float4 w4 = *(const float4*)(Wc2p + col * 4);
      const float gc = gcl[col];
#pragma unroll
      for (int m = 0; m < 2; ++m)
#pragma unroll
        for (int i = 0; i < 4; ++i) {
          const float hv = fmaxf(acc[m][nt][i] + gc, 0.f);
          p[m][i][0] = fmaf(hv, w4.x, p[m][i][0]);
          p[m][i][1] = fmaf(hv, w4.y, p[m][i][1]);
          p[m][i][2] = fmaf(hv, w4.z, p[m][i][2]);
        }
    }
#pragma unroll
    for (int mask = 1; mask <= 8; mask <<= 1)
#pragma unroll
      for (int m = 0; m < 2; ++m)
#pragma unroll
        for (int i = 0; i < 4; ++i)
#pragma unroll
          for (int o = 0; o < 3; ++o) p[m][i][o] += __shfl_xor(p[m][i][o], mask);
    if (fr == 0) {
#pragma unroll
      for (int m = 0; m < 2; ++m)
#pragma unroll
        for (int i = 0; i < 4; ++i) {
          const int row = m * 16 + g4 * 4 + i;
#pragma unroll
          for (int o = 0; o < 3; ++o) red_c[wv][row][o] = p[m][i][o];
        }
    }
  }
  __syncthreads();

  // ---- combine / mask / outputs ----
  if (tid < 32) {
    const int e = tid, m = m0 + e;
    const int ns = nsw[b];
    const bool mk = (m >= cM - ns);
    const float s0  = red_s[0][e][0] + red_s[1][e][0] + red_s[2][e][0] + red_s[3][e][0] + bs2[0];
    const float sv1 = red_s[0][e][1] + red_s[1][e][1] + red_s[2][e][1] + red_s[3][e][1] + bs2[1];
    const float sv2 = red_s[0][e][2] + red_s[1][e][2] + red_s[2][e][2] + red_s[3][e][2] + bs2[2];
    const float sv3 = red_s[0][e][3] + red_s[1][e][3] + red_s[2][e][3] + red_s[3][e][3] + bs2[3];
    const float c0  = red_c[0][e][0] + red_c[1][e][0] + red_c[2][e][0] + red_c[3][e][0] + bc2[0];
    const float c1  = red_c[0][e][1] + red_c[1][e][1] + red_c[2][e][1] + red_c[3][e][1] + bc2[1];
    const float c2  = red_c[0][e][2] + red_c[1][e][2] + red_c[2][e][2] + red_c[3][e][2] + bc2[2];
    const float gt = mk ? (1.f / (1.f + expf(-s0))) : 1.f;
    const float pf = mk ? sv1 : c0;
    const float vp = mk ? sv2 : c1;
    const float vc = mk ? sv3 : c2;
    const float pfc = pf * gt;
    const int bm = b * cM + m;
    gt_w[bm] = gt; wvp_w[bm] = vp; wvc_w[bm] = vc; pfc_w[bm] = pfc;
    out[b * ZROW + m] = pfc;
    out[b * ZROW + cM + cN + m] = gt;
  }
}

// ---------------- v einsums ----------------
__global__ __launch_bounds__(256) void k_v(const float* __restrict__ incP, const float* __restrict__ incC,
                                           const float* __restrict__ wvp, const float* __restrict__ wvc,
                                           const float* __restrict__ invdeg, float* __restrict__ v_w,
                                           float* __restrict__ out) {
  const int wid = blockIdx.x * 4 + (threadIdx.x >> 6);
  const int lane = threadIdx.x & 63;
  const int b = wid / cN, n = wid % cN;
  const size_t rowoff = (size_t)(b * cN + n) * cM + lane * 8;
  const float4 p0 = *(const float4*)(incP + rowoff);
  const float4 p1 = *(const float4*)(incP + rowoff + 4);
  const float4 c0 = *(const float4*)(incC + rowoff);
  const float4 c1 = *(const float4*)(incC + rowoff + 4);
  const float* wp = wvp + b * cM + lane * 8;
  const float* wc = wvc + b * cM + lane * 8;
  float s;
  s = p0.x * wp[0] + p0.y * wp[1] + p0.z * wp[2] + p0.w * wp[3] +
      p1.x * wp[4] + p1.y * wp[5] + p1.z * wp[6] + p1.w * wp[7];
  s += c0.x * wc[0] + c0.y * wc[1] + c0.z * wc[2] + c0.w * wc[3] +
       c1.x * wc[4] + c1.y * wc[5] + c1.z * wc[6] + c1.w * wc[7];
#pragma unroll
  for (int off = 32; off >= 1; off >>= 1) s += __shfl_down(s, off);
  if (lane == 0) {
    float val = invdeg[b * cN + n] * s;
    if (n == 0) val = 1.0f;
    v_w[b * cN + n] = val;
    out[b * ZROW + cM + n] = val;
  }
}

// ---------------- q_fc = (A^T v) * graph_topo ----------------
__global__ __launch_bounds__(256) void k_qfc(const float* __restrict__ A, const float* __restrict__ v_w,
                                             const float* __restrict__ gt_w, float* __restrict__ qfc_w,
                                             float* __restrict__ out) {
  __shared__ float vs[cN];
  const int b = blockIdx.x >> 1;
  const int m = ((blockIdx.x & 1) << 8) + threadIdx.x;
  for (int i = threadIdx.x; i < cN; i += 256) vs[i] = v_w[b * cN + i];
  __syncthreads();
  float s = 0.f;
  for (int n = 0; n < cN; ++n) s = fmaf(A[n * cM + m], vs[n], s);
  const int bm = b * cM + m;
  const float q = s * gt_w[bm];
  qfc_w[bm] = q;
  out[ZBASE + b * CROW + m] = q;
}

// ---------------- pg / qg ----------------
__global__ __launch_bounds__(256) void k_pgqg(const float* __restrict__ A, const float* __restrict__ x,
                                              const float* __restrict__ pfc, const float* __restrict__ qfc,
                                              float* __restrict__ out) {
  const int idx = blockIdx.x * 256 + threadIdx.x;
  if (idx >= cNN) return;
  const int b = idx / cN, n = idx % cN;
  const float* ar = A + (size_t)n * cM;
  const float* pf = pfc + b * cM;
  const float* qf = qfc + b * cM;
  float ps = 0.f, qs = 0.f;
  for (int mm = 0; mm < cM; mm += 4) {
    const float4 ua = *(const float4*)(ar + mm);
    ps += ua.x * pf[mm] + ua.y * pf[mm + 1] + ua.z * pf[mm + 2] + ua.w * pf[mm + 3];
    qs += ua.x * qf[mm] + ua.y * qf[mm + 1] + ua.z * qf[mm + 2] + ua.w * qf[mm + 3];
  }
  out[ZBASE + b * CROW + cM + n] = x[2 * idx] + ps;
  out[ZBASE + b * CROW + cM + cN + n] = x[2 * idx + 1] + qs;
}

extern "C" void kernel_launch(void* const* d_in, const int* in_sizes, int n_in,
                              void* d_out, int out_size, void* d_ws, size_t ws_size,
                              hipStream_t stream) {
  const bool dict_order = (in_sizes[1] == 2 * cE);
  int IEI, INSW, IIVD, IIP, IIC, IA, IW;
  if (dict_order) { IEI = 1; INSW = 2; IIVD = 3; IIP = 4; IIC = 5; IA = 6; IW = 7; }
  else            { IIVD = 1; IIP = 2; IIC = 3; IA = 4; IW = 5; IEI = 17; INSW = 18; }

  const float* x = (const float*)d_in[0];
  const int* ei_raw = (const int*)d_in[IEI];
  const int* nsw_raw = (const int*)d_in[INSW];
  const float* invdeg = (const float*)d_in[IIVD];
  const float* incP = (const float*)d_in[IIP];
  const float* incC = (const float*)d_in[IIC];
  const float* A = (const float*)d_in[IA];
  const float* W1 = (const float*)d_in[IW + 0];
  const float* b1 = (const float*)d_in[IW + 1];
  const float* W2 = (const float*)d_in[IW + 2];
  const float* b2 = (const float*)d_in[IW + 3];
  const float* Ws1 = (const float*)d_in[IW + 4];
  const float* bs1 = (const float*)d_in[IW + 5];
  const float* Ws2 = (const float*)d_in[IW + 6];
  const float* bs2 = (const float*)d_in[IW + 7];
  const float* Wc1 = (const float*)d_in[IW + 8];
  const float* bc1 = (const float*)d_in[IW + 9];
  const float* Wc2 = (const float*)d_in[IW + 10];
  const float* bc2 = (const float*)d_in[IW + 11];
  float* out = (float*)d_out;

  // ---- workspace (~83.6 MB peak, proven available) ----
  char* w = (char*)d_ws;
  auto alloc = [&](size_t bytes) { void* p = (void*)w; w += (bytes + 255) & ~(size_t)255; return p; };
  float* dinv = (float*)alloc((size_t)cNN * 4);
  int* ei = (int*)alloc((size_t)2 * cE * 4);
  int* nsw = (int*)alloc((size_t)cB * 4);
  bf16* hbufA = (bf16*)alloc((size_t)cNN * cH * 2);  // hraw -> h1 -> xg
  bf16* hbufB = (bf16*)alloc((size_t)cNN * cH * 2);  // h2raw
  float* agg = (float*)alloc((size_t)cNN * cH * 4);  // dead after k_reluagg#2
  float* x_g = (float*)alloc((size_t)cB * cH * 4);
  float* gt_w = (float*)alloc((size_t)cB * cM * 4);
  float* wvp_w = (float*)alloc((size_t)cB * cM * 4);
  float* wvc_w = (float*)alloc((size_t)cB * cM * 4);
  float* pfc_w = (float*)alloc((size_t)cB * cM * 4);
  float* qfc_w = (float*)alloc((size_t)cB * cM * 4);
  float* v_w = (float*)alloc((size_t)cB * cN * 4);

  // overlays inside agg (written only after agg's last read):
  bf16* Ws1t = (bf16*)agg;                              // 262144 B
  bf16* Wc1t = (bf16*)((char*)agg + 262144);            // 196608 B
  float* g_s = (float*)((char*)agg + 458752);           // 409600 B
  float* g_c = (float*)((char*)agg + 868352);           // 307200 B
  float* Wc2p = (float*)((char*)agg + 1175552);         // 6144 B

  const int NH = cNN * cH;
  k_norm_idx<<<(2 * cE) / 256, 256, 0, stream>>>(ei_raw, nsw_raw, ei, nsw);
  k_fill<<<(cNN + 255) / 256, 256, 0, stream>>>(dinv, 1.0f, cNN);
  k_deg<<<cE / 256, 256, 0, stream>>>(ei, dinv);
  k_dinv<<<(cNN + 255) / 256, 256, 0, stream>>>(dinv);

  // GCN layer 1
  k_lin1<<<NH / 256, 256, 0, stream>>>(x, W1, b1, hbufA);
  k_scat_lds<<<cB * 4, 256, 0, stream>>>(ei, hbufA, dinv, agg);
  k_reluagg<<<NH / 256, 256, 0, stream>>>(agg, hbufA, dinv, hbufA);

  // GCN layer 2
  k_lin2<<<cNN / 8, 256, 0, stream>>>(hbufA, W2, b2, hbufB);
  k_scat_lds<<<cB * 4, 256, 0, stream>>>(ei, hbufB, dinv, agg);
  k_reluagg<<<NH / 256, 256, 0, stream>>>(agg, hbufB, dinv, hbufA);  // xg

  bf16* xg = hbufA;
  // weight prep + per-batch g vectors (agg now dead; overlays live)
  k_wt<<<512, 256, 0, stream>>>(Ws1, Wc1, Wc2, Ws1t, Wc1t, Wc2p);
  k_xgsum<<<cB, 128, 0, stream>>>(xg, x_g);
  k_gsgc<<<cB, 512, 0, stream>>>(x_g, Ws1, bs1, Wc1, bc1, g_s, g_c);

  // per-edge MLPs on matrix cores
  k_mlp_mfma<<<cB * 16, 256, 0, stream>>>(ei, nsw, xg, Ws1t, Wc1t, g_s, g_c,
                                          Ws2, bs2, Wc2p, bc2,
                                          gt_w, wvp_w, wvc_w, pfc_w, out);

  k_v<<<cB * cN / 4, 256, 0, stream>>>(incP, incC, wvp_w, wvc_w, invdeg, v_w, out);
  k_qfc<<<cB * cM / 256, 256, 0, stream>>>(A, v_w, gt_w, qfc_w, out);
  k_pgqg<<<(cNN + 255) / 256, 256, 0, stream>>>(A, x, pfc_w, qfc_w, out);
}

// Round 10
// 801.213 us; speedup vs baseline: 1.1232x; 1.1232x over previous
//
#include <hip/hip_runtime.h>
#include <hip/hip_bf16.h>

typedef __hip_bfloat16 bf16;
typedef __bf16 bf16x8 __attribute__((ext_vector_type(8)));
typedef float f32x4 __attribute__((ext_vector_type(4)));

static constexpr int cB = 200, cN = 384, cM = 512, cH = 128;
static constexpr int cNN  = cB * cN;     // 76800
static constexpr int cE   = 2 * cB * cM; // 204800 edges
static constexpr int cTWOM = 2 * cM;     // 1024
static constexpr int ZROW = 2 * cM + cN; // 1408
static constexpr int CROW = cM + 2 * cN; // 1280
static constexpr int ZBASE = cB * ZROW;  // 281600

__device__ __forceinline__ float b2f(bf16 x) { return __bfloat162float(x); }
__device__ __forceinline__ bf16  f2b(float x) { return __float2bfloat16(x); }

// ---------------- normalize edge_index / numSwitches (int32 or int64 low words) ----
__global__ __launch_bounds__(256) void k_norm_idx(const int* __restrict__ ei_raw,
                                                  const int* __restrict__ nsw_raw,
                                                  int* __restrict__ ei, int* __restrict__ nsw) {
  int z = 0;
#pragma unroll
  for (int j = 1; j < 64; j += 2) z |= ei_raw[j];
  const int f = (z == 0) ? 1 : 0;
  const int i = blockIdx.x * 256 + threadIdx.x;
  if (i < 2 * cE) ei[i] = ei_raw[i << f];
  if (blockIdx.x == 0 && threadIdx.x < cB) nsw[threadIdx.x] = nsw_raw[threadIdx.x << f];
}

__global__ __launch_bounds__(256) void k_fill(float* p, float v, int count) {
  int i = blockIdx.x * 256 + threadIdx.x;
  if (i < count) p[i] = v;
}

__global__ __launch_bounds__(256) void k_deg(const int* __restrict__ ei, float* deg) {
  int e = blockIdx.x * 256 + threadIdx.x;
  if (e < cE) atomicAdd(&deg[ei[cE + e]], 1.0f);
}

__global__ __launch_bounds__(256) void k_dinv(float* deg) {
  int i = blockIdx.x * 256 + threadIdx.x;
  if (i < cNN) deg[i] = rsqrtf(deg[i]);
}

// ---------------- layer 1 linear: hraw = x@W1 + b1 ----------------
__global__ __launch_bounds__(256) void k_lin1(const float* __restrict__ x, const float* __restrict__ W1,
                                              const float* __restrict__ b1, bf16* __restrict__ hraw) {
  int idx = blockIdx.x * 256 + threadIdx.x;
  if (idx >= cNN * cH) return;
  int n = idx >> 7, h = idx & 127;
  hraw[idx] = f2b(x[2 * n] * W1[h] + x[2 * n + 1] * W1[cH + h] + b1[h]);
}

// ---------------- fused scatter + relu(agg + self), in place ----------------
// block = (batch b, feature-quarter fq). Block touches only f in its fq slice:
// reads h[s, fq] for batch-b edges, then writes h[n, fq] — race-free in place.
__global__ __launch_bounds__(256) void k_scat_fused(const int* __restrict__ ei, bf16* __restrict__ h,
                                                    const float* __restrict__ dinv) {
  constexpr int FQ = 32;
  __shared__ float acc[cN * FQ];   // 48 KB
  __shared__ float nrm[1024];      // 4 KB
  __shared__ int   srcn[1024];     // 4 KB
  __shared__ int   dstn[1024];     // 4 KB
  const int tid = threadIdx.x;
  const int b = blockIdx.x >> 2;
  const int f0 = (blockIdx.x & 3) * FQ;
  for (int i = tid; i < cN * FQ; i += 256) acc[i] = 0.f;
  for (int i = tid; i < 1024; i += 256) {
    const int e = b * cTWOM + i;        // per-batch contiguous edge slice
    const int s = ei[e], d = ei[cE + e];
    srcn[i] = s;
    dstn[i] = (d - b * cN) * FQ;
    nrm[i] = dinv[s] * dinv[d];
  }
  __syncthreads();
  const int f = tid & (FQ - 1);
  const int e0 = tid >> 5;               // 8 edges per 256-thread pass
  for (int ee = e0; ee < 1024; ee += 8) {
    const float v = b2f(h[(size_t)srcn[ee] * cH + f0 + f]) * nrm[ee];
    atomicAdd(&acc[dstn[ee] + f], v);
  }
  __syncthreads();
  for (int i = tid; i < cN * FQ; i += 256) {
    const int n = i / FQ, ff = i - n * FQ;
    const int node = b * cN + n;
    const float dn = dinv[node];
    const size_t gi = (size_t)node * cH + f0 + ff;
    const float val = acc[i] + b2f(h[gi]) * dn * dn;
    h[gi] = f2b(fmaxf(val, 0.0f));
  }
}

// ---------------- layer 2 linear: h2raw = h1@W2 + b2 ----------------
__global__ __launch_bounds__(256) void k_lin2(const bf16* __restrict__ h1, const float* __restrict__ W2,
                                              const float* __restrict__ b2v, bf16* __restrict__ h2raw) {
  __shared__ float w2s[64 * cH];
  __shared__ float ts[8][cH];
  const int tid = threadIdx.x;
  const int n0 = blockIdx.x * 8;
  for (int i = tid; i < 8 * cH; i += 256)
    ts[i >> 7][i & 127] = b2f(h1[(size_t)(n0 + (i >> 7)) * cH + (i & 127)]);
  const int hp = (tid & 63) * 2;
  const int ng = tid >> 6;
  const int e0 = ng, e1 = ng + 4;
  float a00 = 0, a01 = 0, a10 = 0, a11 = 0;
  for (int half = 0; half < 2; ++half) {
    __syncthreads();
    for (int i = tid; i < 64 * cH; i += 256) w2s[i] = W2[half * 64 * cH + i];
    __syncthreads();
    const int kb = half * 64;
#pragma unroll 8
    for (int k = 0; k < 64; ++k) {
      const float w0 = w2s[k * cH + hp];
      const float w1 = w2s[k * cH + hp + 1];
      const float t0 = ts[e0][kb + k];
      const float t1 = ts[e1][kb + k];
      a00 = fmaf(t0, w0, a00); a01 = fmaf(t0, w1, a01);
      a10 = fmaf(t1, w0, a10); a11 = fmaf(t1, w1, a11);
    }
  }
  h2raw[(size_t)(n0 + e0) * cH + hp]     = f2b(a00 + b2v[hp]);
  h2raw[(size_t)(n0 + e0) * cH + hp + 1] = f2b(a01 + b2v[hp + 1]);
  h2raw[(size_t)(n0 + e1) * cH + hp]     = f2b(a10 + b2v[hp]);
  h2raw[(size_t)(n0 + e1) * cH + hp + 1] = f2b(a11 + b2v[hp + 1]);
}

// ---------------- x_g = sum_n xg ----------------
__global__ __launch_bounds__(128) void k_xgsum(const bf16* __restrict__ xg, float* __restrict__ x_g) {
  int b = blockIdx.x, h = threadIdx.x;
  float s = 0.f;
  const bf16* p = xg + (size_t)b * cN * cH + h;
  for (int n = 0; n < cN; ++n) s += b2f(p[(size_t)n * cH]);
  x_g[b * cH + h] = s;
}

// ---------------- weight prep: transposes to bf16 + Wc2 pad to float4 ----------------
__global__ __launch_bounds__(256) void k_wt(const float* __restrict__ Ws1, const float* __restrict__ Wc1,
                                            const float* __restrict__ Wc2,
                                            bf16* __restrict__ Ws1t, bf16* __restrict__ Wc1t,
                                            float* __restrict__ Wc2p) {
  int idx = blockIdx.x * 256 + threadIdx.x;
  if (idx < 512 * 256) {
    int j = idx >> 8, k = idx & 255;
    Ws1t[idx] = f2b(Ws1[k * 512 + j]);
  }
  if (idx < 384 * 256) {
    int j = idx >> 8, k = idx & 255;
    Wc1t[idx] = f2b(Wc1[k * 384 + j]);
  }
  if (idx < 384 * 4) {
    int j = idx >> 2, o = idx & 3;
    Wc2p[idx] = (o < 3) ? Wc2[j * 3 + o] : 0.f;
  }
}

// ---------------- g_s = x_g@Ws1[256:]+bs1 ; g_c = x_g@Wc1[256:]+bc1 (exact, f32) ----------
__global__ __launch_bounds__(512) void k_gsgc(const float* __restrict__ x_g, const float* __restrict__ Ws1,
                                              const float* __restrict__ bs1, const float* __restrict__ Wc1,
                                              const float* __restrict__ bc1, float* __restrict__ g_s,
                                              float* __restrict__ g_c) {
  __shared__ float xs[cH];
  const int b = blockIdx.x, tid = threadIdx.x;
  if (tid < cH) xs[tid] = x_g[b * cH + tid];
  __syncthreads();
  {
    float acc = bs1[tid];
    for (int k = 0; k < cH; ++k) acc = fmaf(xs[k], Ws1[(2 * cH + k) * 512 + tid], acc);
    g_s[b * 512 + tid] = acc;
  }
  if (tid < 384) {
    float acc = bc1[tid];
    for (int k = 0; k < cH; ++k) acc = fmaf(xs[k], Wc1[(2 * cH + k) * 384 + tid], acc);
    g_c[b * 384 + tid] = acc;
  }
}

// ---------------- per-edge MLPs via MFMA: 64 edges/block, col-chunked epilogue ----------
__global__ __launch_bounds__(256) void k_mlp_mfma(
    const int* __restrict__ ei, const int* __restrict__ nsw, const bf16* __restrict__ xg,
    const bf16* __restrict__ Ws1t, const bf16* __restrict__ Wc1t,
    const float* __restrict__ g_s, const float* __restrict__ g_c,
    const float* __restrict__ Ws2, const float* __restrict__ bs2,
    const float* __restrict__ Wc2p, const float* __restrict__ bc2,
    float* __restrict__ gt_w, float* __restrict__ wvp_w, float* __restrict__ wvc_w,
    float* __restrict__ pfc_w, float* __restrict__ out) {
  constexpr int FS = 264;   // feat row stride (bf16)
  __shared__ __align__(16) bf16 feat[64 * FS];    // 33.8 KB
  __shared__ float gsl[512];                      // 2 KB
  __shared__ float gcl[384];                      // 1.5 KB
  __shared__ float red_s[4][64][4];               // 4 KB
  __shared__ float red_c[4][64][4];               // 4 KB

  const int tid = threadIdx.x;
  const int b = blockIdx.x >> 3;
  const int m0 = (blockIdx.x & 7) << 6;    // 64 edges per block
  const int wv = tid >> 6, ln = tid & 63;
  const int fr = ln & 15;
  const int g4 = ln >> 4;            // 0..3
  const int ak = g4 * 8;             // fragment k offset

  // ---- gather feat[e][0:256] = [xg[pn] | xg[cn]]; stage g vectors ----
  {
    const int e = tid >> 2, j = tid & 3;     // 4 threads per edge, 4 uint4 per half each
    const int m = m0 + e;
    const int pn = ei[b * cTWOM + m];
    const int cn = ei[b * cTWOM + cM + m];
    const uint4* ps = (const uint4*)(xg + (size_t)pn * cH);
    const uint4* cs = (const uint4*)(xg + (size_t)cn * cH);
    uint4* fp = (uint4*)(feat + e * FS);
    uint4* fc = (uint4*)(feat + e * FS + 128);
#pragma unroll
    for (int r = 0; r < 4; ++r) {
      fp[j * 4 + r] = ps[j * 4 + r];
      fc[j * 4 + r] = cs[j * 4 + r];
    }
  }
  for (int i = tid; i < 512; i += 256) gsl[i] = g_s[b * 512 + i];
  for (int i = tid; i < 384; i += 256) gcl[i] = g_c[b * 384 + i];
  __syncthreads();

  const bf16* ap = feat + fr * FS + ak;

  // ================= S path: wave cols [wv*128, wv*128+128), 2 chunks x 4 nt ==========
  {
    float p[4][4][4];   // [m][i][o]
#pragma unroll
    for (int m = 0; m < 4; ++m)
#pragma unroll
      for (int i = 0; i < 4; ++i)
#pragma unroll
        for (int o = 0; o < 4; ++o) p[m][i][o] = 0.f;
    const bf16* bp = Ws1t + ((size_t)(wv * 128 + fr)) * 256 + ak;
#pragma unroll
    for (int c = 0; c < 2; ++c) {
      f32x4 acc[4][4];
#pragma unroll
      for (int m = 0; m < 4; ++m)
#pragma unroll
        for (int j = 0; j < 4; ++j) acc[m][j] = f32x4{0.f, 0.f, 0.f, 0.f};
      const bf16* bpc = bp + (size_t)(c * 4) * 16 * 256;
#pragma unroll
      for (int kt = 0; kt < 8; ++kt) {
        const int ko = kt * 32;
        const bf16x8 a0 = *(const bf16x8*)(ap + ko);
        const bf16x8 a1 = *(const bf16x8*)(ap + 16 * FS + ko);
        const bf16x8 a2 = *(const bf16x8*)(ap + 32 * FS + ko);
        const bf16x8 a3 = *(const bf16x8*)(ap + 48 * FS + ko);
#pragma unroll
        for (int j = 0; j < 4; ++j) {
          const bf16x8 bfr = *(const bf16x8*)(bpc + (size_t)j * 16 * 256 + ko);
          acc[0][j] = __builtin_amdgcn_mfma_f32_16x16x32_bf16(a0, bfr, acc[0][j], 0, 0, 0);
          acc[1][j] = __builtin_amdgcn_mfma_f32_16x16x32_bf16(a1, bfr, acc[1][j], 0, 0, 0);
          acc[2][j] = __builtin_amdgcn_mfma_f32_16x16x32_bf16(a2, bfr, acc[2][j], 0, 0, 0);
          acc[3][j] = __builtin_amdgcn_mfma_f32_16x16x32_bf16(a3, bfr, acc[3][j], 0, 0, 0);
        }
      }
      // fold chunk into p (relu + g, second layer)
#pragma unroll
      for (int j = 0; j < 4; ++j) {
        const int col = wv * 128 + (c * 4 + j) * 16 + fr;
        const float4 w4 = *(const float4*)(Ws2 + col * 4);
        const float gs = gsl[col];
#pragma unroll
        for (int m = 0; m < 4; ++m)
#pragma unroll
          for (int i = 0; i < 4; ++i) {
            const float hv = fmaxf(acc[m][j][i] + gs, 0.f);
            p[m][i][0] = fmaf(hv, w4.x, p[m][i][0]);
            p[m][i][1] = fmaf(hv, w4.y, p[m][i][1]);
            p[m][i][2] = fmaf(hv, w4.z, p[m][i][2]);
            p[m][i][3] = fmaf(hv, w4.w, p[m][i][3]);
          }
      }
    }
#pragma unroll
    for (int mask = 1; mask <= 8; mask <<= 1)
#pragma unroll
      for (int m = 0; m < 4; ++m)
#pragma unroll
        for (int i = 0; i < 4; ++i)
#pragma unroll
          for (int o = 0; o < 4; ++o) p[m][i][o] += __shfl_xor(p[m][i][o], mask);
    if (fr == 0) {
#pragma unroll
      for (int m = 0; m < 4; ++m)
#pragma unroll
        for (int i = 0; i < 4; ++i) {
          const int row = m * 16 + g4 * 4 + i;
#pragma unroll
          for (int o = 0; o < 4; ++o) red_s[wv][row][o] = p[m][i][o];
        }
    }
  }

  // ================= C path: wave cols [wv*96, wv*96+96), 2 chunks x 3 nt ============
  {
    float p[4][4][4];
#pragma unroll
    for (int m = 0; m < 4; ++m)
#pragma unroll
      for (int i = 0; i < 4; ++i)
#pragma unroll
        for (int o = 0; o < 4; ++o) p[m][i][o] = 0.f;
    const bf16* bp = Wc1t + ((size_t)(wv * 96 + fr)) * 256 + ak;
#pragma unroll
    for (int c = 0; c < 2; ++c) {
      f32x4 acc[4][3];
#pragma unroll
      for (int m = 0; m < 4; ++m)
#pragma unroll
        for (int j = 0; j < 3; ++j) acc[m][j] = f32x4{0.f, 0.f, 0.f, 0.f};
      const bf16* bpc = bp + (size_t)(c * 3) * 16 * 256;
#pragma unroll
      for (int kt = 0; kt < 8; ++kt) {
        const int ko = kt * 32;
        const bf16x8 a0 = *(const bf16x8*)(ap + ko);
        const bf16x8 a1 = *(const bf16x8*)(ap + 16 * FS + ko);
        const bf16x8 a2 = *(const bf16x8*)(ap + 32 * FS + ko);
        const bf16x8 a3 = *(const bf16x8*)(ap + 48 * FS + ko);
#pragma unroll
        for (int j = 0; j < 3; ++j) {
          const bf16x8 bfr = *(const bf16x8*)(bpc + (size_t)j * 16 * 256 + ko);
          acc[0][j] = __builtin_amdgcn_mfma_f32_16x16x32_bf16(a0, bfr, acc[0][j], 0, 0, 0);
          acc[1][j] = __builtin_amdgcn_mfma_f32_16x16x32_bf16(a1, bfr, acc[1][j], 0, 0, 0);
          acc[2][j] = __builtin_amdgcn_mfma_f32_16x16x32_bf16(a2, bfr, acc[2][j], 0, 0, 0);
          acc[3][j] = __builtin_amdgcn_mfma_f32_16x16x32_bf16(a3, bfr, acc[3][j], 0, 0, 0);
        }
      }
#pragma unroll
      for (int j = 0; j < 3; ++j) {
        const int col = wv * 96 + (c * 3 + j) * 16 + fr;
        const float4 w4 = *(const float4*)(Wc2p + col * 4);
        const float gc = gcl[col];
#pragma unroll
        for (int m = 0; m < 4; ++m)
#pragma unroll
          for (int i = 0; i < 4; ++i) {
            const float hv = fmaxf(acc[m][j][i] + gc, 0.f);
            p[m][i][0] = fmaf(hv, w4.x, p[m][i][0]);
            p[m][i][1] = fmaf(hv, w4.y, p[m][i][1]);
            p[m][i][2] = fmaf(hv, w4.z, p[m][i][2]);
          }
      }
    }
#pragma unroll
    for (int mask = 1; mask <= 8; mask <<= 1)
#pragma unroll
      for (int m = 0; m < 4; ++m)
#pragma unroll
        for (int i = 0; i < 4; ++i)
#pragma unroll
          for (int o = 0; o < 3; ++o) p[m][i][o] += __shfl_xor(p[m][i][o], mask);
    if (fr == 0) {
#pragma unroll
      for (int m = 0; m < 4; ++m)
#pragma unroll
        for (int i = 0; i < 4; ++i) {
          const int row = m * 16 + g4 * 4 + i;
#pragma unroll
          for (int o = 0; o < 3; ++o) red_c[wv][row][o] = p[m][i][o];
        }
    }
  }
  __syncthreads();

  // ---- combine / mask / outputs ----
  if (tid < 64) {
    const int e = tid, m = m0 + e;
    const int ns = nsw[b];
    const bool mk = (m >= cM - ns);
    const float s0  = red_s[0][e][0] + red_s[1][e][0] + red_s[2][e][0] + red_s[3][e][0] + bs2[0];
    const float sv1 = red_s[0][e][1] + red_s[1][e][1] + red_s[2][e][1] + red_s[3][e][1] + bs2[1];
    const float sv2 = red_s[0][e][2] + red_s[1][e][2] + red_s[2][e][2] + red_s[3][e][2] + bs2[2];
    const float sv3 = red_s[0][e][3] + red_s[1][e][3] + red_s[2][e][3] + red_s[3][e][3] + bs2[3];
    const float c0  = red_c[0][e][0] + red_c[1][e][0] + red_c[2][e][0] + red_c[3][e][0] + bc2[0];
    const float c1  = red_c[0][e][1] + red_c[1][e][1] + red_c[2][e][1] + red_c[3][e][1] + bc2[1];
    const float c2  = red_c[0][e][2] + red_c[1][e][2] + red_c[2][e][2] + red_c[3][e][2] + bc2[2];
    const float gt = mk ? (1.f / (1.f + expf(-s0))) : 1.f;
    const float pf = mk ? sv1 : c0;
    const float vp = mk ? sv2 : c1;
    const float vc = mk ? sv3 : c2;
    const float pfc = pf * gt;
    const int bm = b * cM + m;
    gt_w[bm] = gt; wvp_w[bm] = vp; wvc_w[bm] = vc; pfc_w[bm] = pfc;
    out[b * ZROW + m] = pfc;
    out[b * ZROW + cM + cN + m] = gt;
  }
}

// ---------------- v einsums ----------------
__global__ __launch_bounds__(256) void k_v(const float* __restrict__ incP, const float* __restrict__ incC,
                                           const float* __restrict__ wvp, const float* __restrict__ wvc,
                                           const float* __restrict__ invdeg, float* __restrict__ v_w,
                                           float* __restrict__ out) {
  const int wid = blockIdx.x * 4 + (threadIdx.x >> 6);
  const int lane = threadIdx.x & 63;
  const int b = wid / cN, n = wid % cN;
  const size_t rowoff = (size_t)(b * cN + n) * cM + lane * 8;
  const float4 p0 = *(const float4*)(incP + rowoff);
  const float4 p1 = *(const float4*)(incP + rowoff + 4);
  const float4 c0 = *(const float4*)(incC + rowoff);
  const float4 c1 = *(const float4*)(incC + rowoff + 4);
  const float* wp = wvp + b * cM + lane * 8;
  const float* wc = wvc + b * cM + lane * 8;
  float s;
  s = p0.x * wp[0] + p0.y * wp[1] + p0.z * wp[2] + p0.w * wp[3] +
      p1.x * wp[4] + p1.y * wp[5] + p1.z * wp[6] + p1.w * wp[7];
  s += c0.x * wc[0] + c0.y * wc[1] + c0.z * wc[2] + c0.w * wc[3] +
       c1.x * wc[4] + c1.y * wc[5] + c1.z * wc[6] + c1.w * wc[7];
#pragma unroll
  for (int off = 32; off >= 1; off >>= 1) s += __shfl_down(s, off);
  if (lane == 0) {
    float val = invdeg[b * cN + n] * s;
    if (n == 0) val = 1.0f;
    v_w[b * cN + n] = val;
    out[b * ZROW + cM + n] = val;
  }
}

// ---------------- q_fc = (A^T v) * graph_topo ----------------
__global__ __launch_bounds__(256) void k_qfc(const float* __restrict__ A, const float* __restrict__ v_w,
                                             const float* __restrict__ gt_w, float* __restrict__ qfc_w,
                                             float* __restrict__ out) {
  __shared__ float vs[cN];
  const int b = blockIdx.x >> 1;
  const int m = ((blockIdx.x & 1) << 8) + threadIdx.x;
  for (int i = threadIdx.x; i < cN; i += 256) vs[i] = v_w[b * cN + i];
  __syncthreads();
  float s = 0.f;
  for (int n = 0; n < cN; ++n) s = fmaf(A[n * cM + m], vs[n], s);
  const int bm = b * cM + m;
  const float q = s * gt_w[bm];
  qfc_w[bm] = q;
  out[ZBASE + b * CROW + m] = q;
}

// ---------------- pg / qg ----------------
__global__ __launch_bounds__(256) void k_pgqg(const float* __restrict__ A, const float* __restrict__ x,
                                              const float* __restrict__ pfc, const float* __restrict__ qfc,
                                              float* __restrict__ out) {
  const int idx = blockIdx.x * 256 + threadIdx.x;
  if (idx >= cNN) return;
  const int b = idx / cN, n = idx % cN;
  const float* ar = A + (size_t)n * cM;
  const float* pf = pfc + b * cM;
  const float* qf = qfc + b * cM;
  float ps = 0.f, qs = 0.f;
  for (int mm = 0; mm < cM; mm += 4) {
    const float4 ua = *(const float4*)(ar + mm);
    ps += ua.x * pf[mm] + ua.y * pf[mm + 1] + ua.z * pf[mm + 2] + ua.w * pf[mm + 3];
    qs += ua.x * qf[mm] + ua.y * qf[mm + 1] + ua.z * qf[mm + 2] + ua.w * qf[mm + 3];
  }
  out[ZBASE + b * CROW + cM + n] = x[2 * idx] + ps;
  out[ZBASE + b * CROW + cM + cN + n] = x[2 * idx + 1] + qs;
}

extern "C" void kernel_launch(void* const* d_in, const int* in_sizes, int n_in,
                              void* d_out, int out_size, void* d_ws, size_t ws_size,
                              hipStream_t stream) {
  const bool dict_order = (in_sizes[1] == 2 * cE);
  int IEI, INSW, IIVD, IIP, IIC, IA, IW;
  if (dict_order) { IEI = 1; INSW = 2; IIVD = 3; IIP = 4; IIC = 5; IA = 6; IW = 7; }
  else            { IIVD = 1; IIP = 2; IIC = 3; IA = 4; IW = 5; IEI = 17; INSW = 18; }

  const float* x = (const float*)d_in[0];
  const int* ei_raw = (const int*)d_in[IEI];
  const int* nsw_raw = (const int*)d_in[INSW];
  const float* invdeg = (const float*)d_in[IIVD];
  const float* incP = (const float*)d_in[IIP];
  const float* incC = (const float*)d_in[IIC];
  const float* A = (const float*)d_in[IA];
  const float* W1 = (const float*)d_in[IW + 0];
  const float* b1 = (const float*)d_in[IW + 1];
  const float* W2 = (const float*)d_in[IW + 2];
  const float* b2 = (const float*)d_in[IW + 3];
  const float* Ws1 = (const float*)d_in[IW + 4];
  const float* bs1 = (const float*)d_in[IW + 5];
  const float* Ws2 = (const float*)d_in[IW + 6];
  const float* bs2 = (const float*)d_in[IW + 7];
  const float* Wc1 = (const float*)d_in[IW + 8];
  const float* bc1 = (const float*)d_in[IW + 9];
  const float* Wc2 = (const float*)d_in[IW + 10];
  const float* bc2 = (const float*)d_in[IW + 11];
  float* out = (float*)d_out;

  // ---- workspace (~45 MB; well under proven 83.6 MB) ----
  char* w = (char*)d_ws;
  auto alloc = [&](size_t bytes) { void* p = (void*)w; w += (bytes + 255) & ~(size_t)255; return p; };
  float* dinv = (float*)alloc((size_t)cNN * 4);
  int* ei = (int*)alloc((size_t)2 * cE * 4);
  int* nsw = (int*)alloc((size_t)cB * 4);
  bf16* hbufA = (bf16*)alloc((size_t)cNN * cH * 2);  // hraw -> h1 (in place)
  bf16* hbufB = (bf16*)alloc((size_t)cNN * cH * 2);  // h2raw -> xg (in place)
  bf16* Ws1t = (bf16*)alloc((size_t)512 * 256 * 2);
  bf16* Wc1t = (bf16*)alloc((size_t)384 * 256 * 2);
  float* g_s = (float*)alloc((size_t)cB * 512 * 4);
  float* g_c = (float*)alloc((size_t)cB * 384 * 4);
  float* Wc2p = (float*)alloc((size_t)384 * 4 * 4);
  float* x_g = (float*)alloc((size_t)cB * cH * 4);
  float* gt_w = (float*)alloc((size_t)cB * cM * 4);
  float* wvp_w = (float*)alloc((size_t)cB * cM * 4);
  float* wvc_w = (float*)alloc((size_t)cB * cM * 4);
  float* pfc_w = (float*)alloc((size_t)cB * cM * 4);
  float* qfc_w = (float*)alloc((size_t)cB * cM * 4);
  float* v_w = (float*)alloc((size_t)cB * cN * 4);

  const int NH = cNN * cH;
  k_norm_idx<<<(2 * cE) / 256, 256, 0, stream>>>(ei_raw, nsw_raw, ei, nsw);
  k_fill<<<(cNN + 255) / 256, 256, 0, stream>>>(dinv, 1.0f, cNN);
  k_deg<<<cE / 256, 256, 0, stream>>>(ei, dinv);
  k_dinv<<<(cNN + 255) / 256, 256, 0, stream>>>(dinv);

  // GCN layer 1 (scatter fused with relu+self, in place)
  k_lin1<<<NH / 256, 256, 0, stream>>>(x, W1, b1, hbufA);
  k_scat_fused<<<cB * 4, 256, 0, stream>>>(ei, hbufA, dinv);       // h1 in hbufA

  // GCN layer 2
  k_lin2<<<cNN / 8, 256, 0, stream>>>(hbufA, W2, b2, hbufB);
  k_scat_fused<<<cB * 4, 256, 0, stream>>>(ei, hbufB, dinv);       // xg in hbufB

  bf16* xg = hbufB;
  k_wt<<<512, 256, 0, stream>>>(Ws1, Wc1, Wc2, Ws1t, Wc1t, Wc2p);
  k_xgsum<<<cB, 128, 0, stream>>>(xg, x_g);
  k_gsgc<<<cB, 512, 0, stream>>>(x_g, Ws1, bs1, Wc1, bc1, g_s, g_c);

  // per-edge MLPs on matrix cores (64 edges/block)
  k_mlp_mfma<<<cB * 8, 256, 0, stream>>>(ei, nsw, xg, Ws1t, Wc1t, g_s, g_c,
                                         Ws2, bs2, Wc2p, bc2,
                                         gt_w, wvp_w, wvc_w, pfc_w, out);

  k_v<<<cB * cN / 4, 256, 0, stream>>>(incP, incC, wvp_w, wvc_w, invdeg, v_w, out);
  k_qfc<<<cB * cM / 256, 256, 0, stream>>>(A, v_w, gt_w, qfc_w, out);
  k_pgqg<<<(cNN + 255) / 256, 256, 0, stream>>>(A, x, pfc_w, qfc_w, out);
}

// Round 11
// 731.036 us; speedup vs baseline: 1.2311x; 1.0960x over previous
//
#include <hip/hip_runtime.h>
#include <hip/hip_bf16.h>

typedef __hip_bfloat16 bf16;
typedef __bf16 bf16x8 __attribute__((ext_vector_type(8)));
typedef float f32x4 __attribute__((ext_vector_type(4)));

static constexpr int cB = 200, cN = 384, cM = 512, cH = 128;
static constexpr int cNN  = cB * cN;     // 76800
static constexpr int cE   = 2 * cB * cM; // 204800 edges
static constexpr int cTWOM = 2 * cM;     // 1024
static constexpr int ZROW = 2 * cM + cN; // 1408
static constexpr int CROW = cM + 2 * cN; // 1280
static constexpr int ZBASE = cB * ZROW;  // 281600

__device__ __forceinline__ float b2f(bf16 x) { return __bfloat162float(x); }
__device__ __forceinline__ bf16  f2b(float x) { return __float2bfloat16(x); }

// ---------------- normalize edge_index / numSwitches (int32 or int64 low words) ----
__global__ __launch_bounds__(256) void k_norm_idx(const int* __restrict__ ei_raw,
                                                  const int* __restrict__ nsw_raw,
                                                  int* __restrict__ ei, int* __restrict__ nsw) {
  int z = 0;
#pragma unroll
  for (int j = 1; j < 64; j += 2) z |= ei_raw[j];
  const int f = (z == 0) ? 1 : 0;
  const int i = blockIdx.x * 256 + threadIdx.x;
  if (i < 2 * cE) ei[i] = ei_raw[i << f];
  if (blockIdx.x == 0 && threadIdx.x < cB) nsw[threadIdx.x] = nsw_raw[threadIdx.x << f];
}

__global__ __launch_bounds__(256) void k_fill(float* p, float v, int count) {
  int i = blockIdx.x * 256 + threadIdx.x;
  if (i < count) p[i] = v;
}

__global__ __launch_bounds__(256) void k_deg(const int* __restrict__ ei, float* deg) {
  int e = blockIdx.x * 256 + threadIdx.x;
  if (e < cE) atomicAdd(&deg[ei[cE + e]], 1.0f);
}

__global__ __launch_bounds__(256) void k_dinv(float* deg) {
  int i = blockIdx.x * 256 + threadIdx.x;
  if (i < cNN) deg[i] = rsqrtf(deg[i]);
}

// ---------------- layer 1 linear: hraw = x@W1 + b1 ----------------
__global__ __launch_bounds__(256) void k_lin1(const float* __restrict__ x, const float* __restrict__ W1,
                                              const float* __restrict__ b1, bf16* __restrict__ hraw) {
  int idx = blockIdx.x * 256 + threadIdx.x;
  if (idx >= cNN * cH) return;
  int n = idx >> 7, h = idx & 127;
  hraw[idx] = f2b(x[2 * n] * W1[h] + x[2 * n + 1] * W1[cH + h] + b1[h]);
}

// ---------------- fused scatter + relu(agg + self), in place ----------------
// block = (batch b, feature-sixteenth fq). Block exclusively owns (batch, f-slice):
// reads h[s, fs] for batch-b edges (before barrier), writes h[n, fs] after barrier.
__global__ __launch_bounds__(512) void k_scat_fused(const int* __restrict__ ei, bf16* __restrict__ h,
                                                    const float* __restrict__ dinv) {
  constexpr int FQ = 16;
  __shared__ float acc[cN * FQ];   // 24 KB
  __shared__ float nrm[1024];      // 4 KB
  __shared__ int   srcn[1024];     // 4 KB
  __shared__ int   dstn[1024];     // 4 KB
  const int tid = threadIdx.x;
  const int b = blockIdx.x >> 3;
  const int f0 = (blockIdx.x & 7) * FQ;
  for (int i = tid; i < cN * FQ; i += 512) acc[i] = 0.f;
  for (int i = tid; i < 1024; i += 512) {
    const int e = b * cTWOM + i;        // per-batch contiguous edge slice
    const int s = ei[e], d = ei[cE + e];
    srcn[i] = s;
    dstn[i] = (d - b * cN) * FQ;
    nrm[i] = dinv[s] * dinv[d];
  }
  __syncthreads();
  const int f = tid & (FQ - 1);
  const int e0 = tid >> 4;               // 32 edge-groups; 32 iterations/thread
#pragma unroll 8
  for (int ee = e0; ee < 1024; ee += 32) {
    const float v = b2f(h[(size_t)srcn[ee] * cH + f0 + f]) * nrm[ee];
    atomicAdd(&acc[dstn[ee] + f], v);
  }
  __syncthreads();
  for (int i = tid; i < cN * FQ; i += 512) {
    const int n = i / FQ, ff = i - n * FQ;
    const int node = b * cN + n;
    const float dn = dinv[node];
    const size_t gi = (size_t)node * cH + f0 + ff;
    const float val = acc[i] + b2f(h[gi]) * dn * dn;
    h[gi] = f2b(fmaxf(val, 0.0f));
  }
}

// ---------------- layer 2 linear: h2raw = h1@W2 + b2 ----------------
__global__ __launch_bounds__(256) void k_lin2(const bf16* __restrict__ h1, const float* __restrict__ W2,
                                              const float* __restrict__ b2v, bf16* __restrict__ h2raw) {
  __shared__ float w2s[64 * cH];
  __shared__ float ts[8][cH];
  const int tid = threadIdx.x;
  const int n0 = blockIdx.x * 8;
  for (int i = tid; i < 8 * cH; i += 256)
    ts[i >> 7][i & 127] = b2f(h1[(size_t)(n0 + (i >> 7)) * cH + (i & 127)]);
  const int hp = (tid & 63) * 2;
  const int ng = tid >> 6;
  const int e0 = ng, e1 = ng + 4;
  float a00 = 0, a01 = 0, a10 = 0, a11 = 0;
  for (int half = 0; half < 2; ++half) {
    __syncthreads();
    for (int i = tid; i < 64 * cH; i += 256) w2s[i] = W2[half * 64 * cH + i];
    __syncthreads();
    const int kb = half * 64;
#pragma unroll 8
    for (int k = 0; k < 64; ++k) {
      const float w0 = w2s[k * cH + hp];
      const float w1 = w2s[k * cH + hp + 1];
      const float t0 = ts[e0][kb + k];
      const float t1 = ts[e1][kb + k];
      a00 = fmaf(t0, w0, a00); a01 = fmaf(t0, w1, a01);
      a10 = fmaf(t1, w0, a10); a11 = fmaf(t1, w1, a11);
    }
  }
  h2raw[(size_t)(n0 + e0) * cH + hp]     = f2b(a00 + b2v[hp]);
  h2raw[(size_t)(n0 + e0) * cH + hp + 1] = f2b(a01 + b2v[hp + 1]);
  h2raw[(size_t)(n0 + e1) * cH + hp]     = f2b(a10 + b2v[hp]);
  h2raw[(size_t)(n0 + e1) * cH + hp + 1] = f2b(a11 + b2v[hp + 1]);
}

// ---------------- x_g = sum_n xg ----------------
__global__ __launch_bounds__(128) void k_xgsum(const bf16* __restrict__ xg, float* __restrict__ x_g) {
  int b = blockIdx.x, h = threadIdx.x;
  float s = 0.f;
  const bf16* p = xg + (size_t)b * cN * cH + h;
  for (int n = 0; n < cN; ++n) s += b2f(p[(size_t)n * cH]);
  x_g[b * cH + h] = s;
}

// ---------------- weight prep: transposes to bf16 + Wc2 pad to float4 ----------------
__global__ __launch_bounds__(256) void k_wt(const float* __restrict__ Ws1, const float* __restrict__ Wc1,
                                            const float* __restrict__ Wc2,
                                            bf16* __restrict__ Ws1t, bf16* __restrict__ Wc1t,
                                            float* __restrict__ Wc2p) {
  int idx = blockIdx.x * 256 + threadIdx.x;
  if (idx < 512 * 256) {
    int j = idx >> 8, k = idx & 255;
    Ws1t[idx] = f2b(Ws1[k * 512 + j]);
  }
  if (idx < 384 * 256) {
    int j = idx >> 8, k = idx & 255;
    Wc1t[idx] = f2b(Wc1[k * 384 + j]);
  }
  if (idx < 384 * 4) {
    int j = idx >> 2, o = idx & 3;
    Wc2p[idx] = (o < 3) ? Wc2[j * 3 + o] : 0.f;
  }
}

// ---------------- g_s = x_g@Ws1[256:]+bs1 ; g_c = x_g@Wc1[256:]+bc1 (exact, f32) ----------
__global__ __launch_bounds__(512) void k_gsgc(const float* __restrict__ x_g, const float* __restrict__ Ws1,
                                              const float* __restrict__ bs1, const float* __restrict__ Wc1,
                                              const float* __restrict__ bc1, float* __restrict__ g_s,
                                              float* __restrict__ g_c) {
  __shared__ float xs[cH];
  const int b = blockIdx.x, tid = threadIdx.x;
  if (tid < cH) xs[tid] = x_g[b * cH + tid];
  __syncthreads();
  {
    float acc = bs1[tid];
    for (int k = 0; k < cH; ++k) acc = fmaf(xs[k], Ws1[(2 * cH + k) * 512 + tid], acc);
    g_s[b * 512 + tid] = acc;
  }
  if (tid < 384) {
    float acc = bc1[tid];
    for (int k = 0; k < cH; ++k) acc = fmaf(xs[k], Wc1[(2 * cH + k) * 384 + tid], acc);
    g_c[b * 384 + tid] = acc;
  }
}

// ---------------- per-edge MLPs via MFMA: 64 edges/block, col-chunked epilogue ----------
__global__ __launch_bounds__(256) void k_mlp_mfma(
    const int* __restrict__ ei, const int* __restrict__ nsw, const bf16* __restrict__ xg,
    const bf16* __restrict__ Ws1t, const bf16* __restrict__ Wc1t,
    const float* __restrict__ g_s, const float* __restrict__ g_c,
    const float* __restrict__ Ws2, const float* __restrict__ bs2,
    const float* __restrict__ Wc2p, const float* __restrict__ bc2,
    float* __restrict__ gt_w, float* __restrict__ wvp_w, float* __restrict__ wvc_w,
    float* __restrict__ pfc_w, float* __restrict__ out) {
  constexpr int FS = 264;   // feat row stride (bf16)
  __shared__ __align__(16) bf16 feat[64 * FS];    // 33.8 KB
  __shared__ float gsl[512];                      // 2 KB
  __shared__ float gcl[384];                      // 1.5 KB
  __shared__ float red_s[4][64][4];               // 4 KB
  __shared__ float red_c[4][64][4];               // 4 KB

  const int tid = threadIdx.x;
  const int b = blockIdx.x >> 3;
  const int m0 = (blockIdx.x & 7) << 6;    // 64 edges per block
  const int wv = tid >> 6, ln = tid & 63;
  const int fr = ln & 15;
  const int g4 = ln >> 4;            // 0..3
  const int ak = g4 * 8;             // fragment k offset

  // ---- gather feat[e][0:256] = [xg[pn] | xg[cn]]; stage g vectors ----
  {
    const int e = tid >> 2, j = tid & 3;     // 4 threads per edge, 4 uint4 per half each
    const int m = m0 + e;
    const int pn = ei[b * cTWOM + m];
    const int cn = ei[b * cTWOM + cM + m];
    const uint4* ps = (const uint4*)(xg + (size_t)pn * cH);
    const uint4* cs = (const uint4*)(xg + (size_t)cn * cH);
    uint4* fp = (uint4*)(feat + e * FS);
    uint4* fc = (uint4*)(feat + e * FS + 128);
#pragma unroll
    for (int r = 0; r < 4; ++r) {
      fp[j * 4 + r] = ps[j * 4 + r];
      fc[j * 4 + r] = cs[j * 4 + r];
    }
  }
  for (int i = tid; i < 512; i += 256) gsl[i] = g_s[b * 512 + i];
  for (int i = tid; i < 384; i += 256) gcl[i] = g_c[b * 384 + i];
  __syncthreads();

  const bf16* ap = feat + fr * FS + ak;

  // ================= S path: wave cols [wv*128, wv*128+128), 2 chunks x 4 nt ==========
  {
    float p[4][4][4];   // [m][i][o]
#pragma unroll
    for (int m = 0; m < 4; ++m)
#pragma unroll
      for (int i = 0; i < 4; ++i)
#pragma unroll
        for (int o = 0; o < 4; ++o) p[m][i][o] = 0.f;
    const bf16* bp = Ws1t + ((size_t)(wv * 128 + fr)) * 256 + ak;
#pragma unroll
    for (int c = 0; c < 2; ++c) {
      f32x4 acc[4][4];
#pragma unroll
      for (int m = 0; m < 4; ++m)
#pragma unroll
        for (int j = 0; j < 4; ++j) acc[m][j] = f32x4{0.f, 0.f, 0.f, 0.f};
      const bf16* bpc = bp + (size_t)(c * 4) * 16 * 256;
#pragma unroll
      for (int kt = 0; kt < 8; ++kt) {
        const int ko = kt * 32;
        const bf16x8 a0 = *(const bf16x8*)(ap + ko);
        const bf16x8 a1 = *(const bf16x8*)(ap + 16 * FS + ko);
        const bf16x8 a2 = *(const bf16x8*)(ap + 32 * FS + ko);
        const bf16x8 a3 = *(const bf16x8*)(ap + 48 * FS + ko);
#pragma unroll
        for (int j = 0; j < 4; ++j) {
          const bf16x8 bfr = *(const bf16x8*)(bpc + (size_t)j * 16 * 256 + ko);
          acc[0][j] = __builtin_amdgcn_mfma_f32_16x16x32_bf16(a0, bfr, acc[0][j], 0, 0, 0);
          acc[1][j] = __builtin_amdgcn_mfma_f32_16x16x32_bf16(a1, bfr, acc[1][j], 0, 0, 0);
          acc[2][j] = __builtin_amdgcn_mfma_f32_16x16x32_bf16(a2, bfr, acc[2][j], 0, 0, 0);
          acc[3][j] = __builtin_amdgcn_mfma_f32_16x16x32_bf16(a3, bfr, acc[3][j], 0, 0, 0);
        }
      }
      // fold chunk into p (relu + g, second layer)
#pragma unroll
      for (int j = 0; j < 4; ++j) {
        const int col = wv * 128 + (c * 4 + j) * 16 + fr;
        const float4 w4 = *(const float4*)(Ws2 + col * 4);
        const float gs = gsl[col];
#pragma unroll
        for (int m = 0; m < 4; ++m)
#pragma unroll
          for (int i = 0; i < 4; ++i) {
            const float hv = fmaxf(acc[m][j][i] + gs, 0.f);
            p[m][i][0] = fmaf(hv, w4.x, p[m][i][0]);
            p[m][i][1] = fmaf(hv, w4.y, p[m][i][1]);
            p[m][i][2] = fmaf(hv, w4.z, p[m][i][2]);
            p[m][i][3] = fmaf(hv, w4.w, p[m][i][3]);
          }
      }
    }
#pragma unroll
    for (int mask = 1; mask <= 8; mask <<= 1)
#pragma unroll
      for (int m = 0; m < 4; ++m)
#pragma unroll
        for (int i = 0; i < 4; ++i)
#pragma unroll
          for (int o = 0; o < 4; ++o) p[m][i][o] += __shfl_xor(p[m][i][o], mask);
    if (fr == 0) {
#pragma unroll
      for (int m = 0; m < 4; ++m)
#pragma unroll
        for (int i = 0; i < 4; ++i) {
          const int row = m * 16 + g4 * 4 + i;
#pragma unroll
          for (int o = 0; o < 4; ++o) red_s[wv][row][o] = p[m][i][o];
        }
    }
  }

  // ================= C path: wave cols [wv*96, wv*96+96), 2 chunks x 3 nt ============
  {
    float p[4][4][4];
#pragma unroll
    for (int m = 0; m < 4; ++m)
#pragma unroll
      for (int i = 0; i < 4; ++i)
#pragma unroll
        for (int o = 0; o < 4; ++o) p[m][i][o] = 0.f;
    const bf16* bp = Wc1t + ((size_t)(wv * 96 + fr)) * 256 + ak;
#pragma unroll
    for (int c = 0; c < 2; ++c) {
      f32x4 acc[4][3];
#pragma unroll
      for (int m = 0; m < 4; ++m)
#pragma unroll
        for (int j = 0; j < 3; ++j) acc[m][j] = f32x4{0.f, 0.f, 0.f, 0.f};
      const bf16* bpc = bp + (size_t)(c * 3) * 16 * 256;
#pragma unroll
      for (int kt = 0; kt < 8; ++kt) {
        const int ko = kt * 32;
        const bf16x8 a0 = *(const bf16x8*)(ap + ko);
        const bf16x8 a1 = *(const bf16x8*)(ap + 16 * FS + ko);
        const bf16x8 a2 = *(const bf16x8*)(ap + 32 * FS + ko);
        const bf16x8 a3 = *(const bf16x8*)(ap + 48 * FS + ko);
#pragma unroll
        for (int j = 0; j < 3; ++j) {
          const bf16x8 bfr = *(const bf16x8*)(bpc + (size_t)j * 16 * 256 + ko);
          acc[0][j] = __builtin_amdgcn_mfma_f32_16x16x32_bf16(a0, bfr, acc[0][j], 0, 0, 0);
          acc[1][j] = __builtin_amdgcn_mfma_f32_16x16x32_bf16(a1, bfr, acc[1][j], 0, 0, 0);
          acc[2][j] = __builtin_amdgcn_mfma_f32_16x16x32_bf16(a2, bfr, acc[2][j], 0, 0, 0);
          acc[3][j] = __builtin_amdgcn_mfma_f32_16x16x32_bf16(a3, bfr, acc[3][j], 0, 0, 0);
        }
      }
#pragma unroll
      for (int j = 0; j < 3; ++j) {
        const int col = wv * 96 + (c * 3 + j) * 16 + fr;
        const float4 w4 = *(const float4*)(Wc2p + col * 4);
        const float gc = gcl[col];
#pragma unroll
        for (int m = 0; m < 4; ++m)
#pragma unroll
          for (int i = 0; i < 4; ++i) {
            const float hv = fmaxf(acc[m][j][i] + gc, 0.f);
            p[m][i][0] = fmaf(hv, w4.x, p[m][i][0]);
            p[m][i][1] = fmaf(hv, w4.y, p[m][i][1]);
            p[m][i][2] = fmaf(hv, w4.z, p[m][i][2]);
          }
      }
    }
#pragma unroll
    for (int mask = 1; mask <= 8; mask <<= 1)
#pragma unroll
      for (int m = 0; m < 4; ++m)
#pragma unroll
        for (int i = 0; i < 4; ++i)
#pragma unroll
          for (int o = 0; o < 3; ++o) p[m][i][o] += __shfl_xor(p[m][i][o], mask);
    if (fr == 0) {
#pragma unroll
      for (int m = 0; m < 4; ++m)
#pragma unroll
        for (int i = 0; i < 4; ++i) {
          const int row = m * 16 + g4 * 4 + i;
#pragma unroll
          for (int o = 0; o < 3; ++o) red_c[wv][row][o] = p[m][i][o];
        }
    }
  }
  __syncthreads();

  // ---- combine / mask / outputs ----
  if (tid < 64) {
    const int e = tid, m = m0 + e;
    const int ns = nsw[b];
    const bool mk = (m >= cM - ns);
    const float s0  = red_s[0][e][0] + red_s[1][e][0] + red_s[2][e][0] + red_s[3][e][0] + bs2[0];
    const float sv1 = red_s[0][e][1] + red_s[1][e][1] + red_s[2][e][1] + red_s[3][e][1] + bs2[1];
    const float sv2 = red_s[0][e][2] + red_s[1][e][2] + red_s[2][e][2] + red_s[3][e][2] + bs2[2];
    const float sv3 = red_s[0][e][3] + red_s[1][e][3] + red_s[2][e][3] + red_s[3][e][3] + bs2[3];
    const float c0  = red_c[0][e][0] + red_c[1][e][0] + red_c[2][e][0] + red_c[3][e][0] + bc2[0];
    const float c1  = red_c[0][e][1] + red_c[1][e][1] + red_c[2][e][1] + red_c[3][e][1] + bc2[1];
    const float c2  = red_c[0][e][2] + red_c[1][e][2] + red_c[2][e][2] + red_c[3][e][2] + bc2[2];
    const float gt = mk ? (1.f / (1.f + expf(-s0))) : 1.f;
    const float pf = mk ? sv1 : c0;
    const float vp = mk ? sv2 : c1;
    const float vc = mk ? sv3 : c2;
    const float pfc = pf * gt;
    const int bm = b * cM + m;
    gt_w[bm] = gt; wvp_w[bm] = vp; wvc_w[bm] = vc; pfc_w[bm] = pfc;
    out[b * ZROW + m] = pfc;
    out[b * ZROW + cM + cN + m] = gt;
  }
}

// ---------------- v einsums ----------------
__global__ __launch_bounds__(256) void k_v(const float* __restrict__ incP, const float* __restrict__ incC,
                                           const float* __restrict__ wvp, const float* __restrict__ wvc,
                                           const float* __restrict__ invdeg, float* __restrict__ v_w,
                                           float* __restrict__ out) {
  const int wid = blockIdx.x * 4 + (threadIdx.x >> 6);
  const int lane = threadIdx.x & 63;
  const int b = wid / cN, n = wid % cN;
  const size_t rowoff = (size_t)(b * cN + n) * cM + lane * 8;
  const float4 p0 = *(const float4*)(incP + rowoff);
  const float4 p1 = *(const float4*)(incP + rowoff + 4);
  const float4 c0 = *(const float4*)(incC + rowoff);
  const float4 c1 = *(const float4*)(incC + rowoff + 4);
  const float* wp = wvp + b * cM + lane * 8;
  const float* wc = wvc + b * cM + lane * 8;
  float s;
  s = p0.x * wp[0] + p0.y * wp[1] + p0.z * wp[2] + p0.w * wp[3] +
      p1.x * wp[4] + p1.y * wp[5] + p1.z * wp[6] + p1.w * wp[7];
  s += c0.x * wc[0] + c0.y * wc[1] + c0.z * wc[2] + c0.w * wc[3] +
       c1.x * wc[4] + c1.y * wc[5] + c1.z * wc[6] + c1.w * wc[7];
#pragma unroll
  for (int off = 32; off >= 1; off >>= 1) s += __shfl_down(s, off);
  if (lane == 0) {
    float val = invdeg[b * cN + n] * s;
    if (n == 0) val = 1.0f;
    v_w[b * cN + n] = val;
    out[b * ZROW + cM + n] = val;
  }
}

// ---------------- q_fc = (A^T v) * graph_topo ----------------
__global__ __launch_bounds__(256) void k_qfc(const float* __restrict__ A, const float* __restrict__ v_w,
                                             const float* __restrict__ gt_w, float* __restrict__ qfc_w,
                                             float* __restrict__ out) {
  __shared__ float vs[cN];
  const int b = blockIdx.x >> 1;
  const int m = ((blockIdx.x & 1) << 8) + threadIdx.x;
  for (int i = threadIdx.x; i < cN; i += 256) vs[i] = v_w[b * cN + i];
  __syncthreads();
  float s = 0.f;
  for (int n = 0; n < cN; ++n) s = fmaf(A[n * cM + m], vs[n], s);
  const int bm = b * cM + m;
  const float q = s * gt_w[bm];
  qfc_w[bm] = q;
  out[ZBASE + b * CROW + m] = q;
}

// ---------------- pg / qg ----------------
__global__ __launch_bounds__(256) void k_pgqg(const float* __restrict__ A, const float* __restrict__ x,
                                              const float* __restrict__ pfc, const float* __restrict__ qfc,
                                              float* __restrict__ out) {
  const int idx = blockIdx.x * 256 + threadIdx.x;
  if (idx >= cNN) return;
  const int b = idx / cN, n = idx % cN;
  const float* ar = A + (size_t)n * cM;
  const float* pf = pfc + b * cM;
  const float* qf = qfc + b * cM;
  float ps = 0.f, qs = 0.f;
  for (int mm = 0; mm < cM; mm += 4) {
    const float4 ua = *(const float4*)(ar + mm);
    ps += ua.x * pf[mm] + ua.y * pf[mm + 1] + ua.z * pf[mm + 2] + ua.w * pf[mm + 3];
    qs += ua.x * qf[mm] + ua.y * qf[mm + 1] + ua.z * qf[mm + 2] + ua.w * qf[mm + 3];
  }
  out[ZBASE + b * CROW + cM + n] = x[2 * idx] + ps;
  out[ZBASE + b * CROW + cM + cN + n] = x[2 * idx + 1] + qs;
}

extern "C" void kernel_launch(void* const* d_in, const int* in_sizes, int n_in,
                              void* d_out, int out_size, void* d_ws, size_t ws_size,
                              hipStream_t stream) {
  const bool dict_order = (in_sizes[1] == 2 * cE);
  int IEI, INSW, IIVD, IIP, IIC, IA, IW;
  if (dict_order) { IEI = 1; INSW = 2; IIVD = 3; IIP = 4; IIC = 5; IA = 6; IW = 7; }
  else            { IIVD = 1; IIP = 2; IIC = 3; IA = 4; IW = 5; IEI = 17; INSW = 18; }

  const float* x = (const float*)d_in[0];
  const int* ei_raw = (const int*)d_in[IEI];
  const int* nsw_raw = (const int*)d_in[INSW];
  const float* invdeg = (const float*)d_in[IIVD];
  const float* incP = (const float*)d_in[IIP];
  const float* incC = (const float*)d_in[IIC];
  const float* A = (const float*)d_in[IA];
  const float* W1 = (const float*)d_in[IW + 0];
  const float* b1 = (const float*)d_in[IW + 1];
  const float* W2 = (const float*)d_in[IW + 2];
  const float* b2 = (const float*)d_in[IW + 3];
  const float* Ws1 = (const float*)d_in[IW + 4];
  const float* bs1 = (const float*)d_in[IW + 5];
  const float* Ws2 = (const float*)d_in[IW + 6];
  const float* bs2 = (const float*)d_in[IW + 7];
  const float* Wc1 = (const float*)d_in[IW + 8];
  const float* bc1 = (const float*)d_in[IW + 9];
  const float* Wc2 = (const float*)d_in[IW + 10];
  const float* bc2 = (const float*)d_in[IW + 11];
  float* out = (float*)d_out;

  // ---- workspace (~45 MB; well under proven 83.6 MB) ----
  char* w = (char*)d_ws;
  auto alloc = [&](size_t bytes) { void* p = (void*)w; w += (bytes + 255) & ~(size_t)255; return p; };
  float* dinv = (float*)alloc((size_t)cNN * 4);
  int* ei = (int*)alloc((size_t)2 * cE * 4);
  int* nsw = (int*)alloc((size_t)cB * 4);
  bf16* hbufA = (bf16*)alloc((size_t)cNN * cH * 2);  // hraw -> h1 (in place)
  bf16* hbufB = (bf16*)alloc((size_t)cNN * cH * 2);  // h2raw -> xg (in place)
  bf16* Ws1t = (bf16*)alloc((size_t)512 * 256 * 2);
  bf16* Wc1t = (bf16*)alloc((size_t)384 * 256 * 2);
  float* g_s = (float*)alloc((size_t)cB * 512 * 4);
  float* g_c = (float*)alloc((size_t)cB * 384 * 4);
  float* Wc2p = (float*)alloc((size_t)384 * 4 * 4);
  float* x_g = (float*)alloc((size_t)cB * cH * 4);
  float* gt_w = (float*)alloc((size_t)cB * cM * 4);
  float* wvp_w = (float*)alloc((size_t)cB * cM * 4);
  float* wvc_w = (float*)alloc((size_t)cB * cM * 4);
  float* pfc_w = (float*)alloc((size_t)cB * cM * 4);
  float* qfc_w = (float*)alloc((size_t)cB * cM * 4);
  float* v_w = (float*)alloc((size_t)cB * cN * 4);

  const int NH = cNN * cH;
  k_norm_idx<<<(2 * cE) / 256, 256, 0, stream>>>(ei_raw, nsw_raw, ei, nsw);
  k_fill<<<(cNN + 255) / 256, 256, 0, stream>>>(dinv, 1.0f, cNN);
  k_deg<<<cE / 256, 256, 0, stream>>>(ei, dinv);
  k_dinv<<<(cNN + 255) / 256, 256, 0, stream>>>(dinv);

  // GCN layer 1 (scatter fused with relu+self, in place)
  k_lin1<<<NH / 256, 256, 0, stream>>>(x, W1, b1, hbufA);
  k_scat_fused<<<cB * 8, 512, 0, stream>>>(ei, hbufA, dinv);       // h1 in hbufA

  // GCN layer 2
  k_lin2<<<cNN / 8, 256, 0, stream>>>(hbufA, W2, b2, hbufB);
  k_scat_fused<<<cB * 8, 512, 0, stream>>>(ei, hbufB, dinv);       // xg in hbufB

  bf16* xg = hbufB;
  k_wt<<<512, 256, 0, stream>>>(Ws1, Wc1, Wc2, Ws1t, Wc1t, Wc2p);
  k_xgsum<<<cB, 128, 0, stream>>>(xg, x_g);
  k_gsgc<<<cB, 512, 0, stream>>>(x_g, Ws1, bs1, Wc1, bc1, g_s, g_c);

  // per-edge MLPs on matrix cores (64 edges/block)
  k_mlp_mfma<<<cB * 8, 256, 0, stream>>>(ei, nsw, xg, Ws1t, Wc1t, g_s, g_c,
                                         Ws2, bs2, Wc2p, bc2,
                                         gt_w, wvp_w, wvc_w, pfc_w, out);

  k_v<<<cB * cN / 4, 256, 0, stream>>>(incP, incC, wvp_w, wvc_w, invdeg, v_w, out);
  k_qfc<<<cB * cM / 256, 256, 0, stream>>>(A, v_w, gt_w, qfc_w, out);
  k_pgqg<<<(cNN + 255) / 256, 256, 0, stream>>>(A, x, pfc_w, qfc_w, out);
}

// Round 12
// 479.157 us; speedup vs baseline: 1.8782x; 1.5257x over previous
//
#include <hip/hip_runtime.h>
#include <hip/hip_bf16.h>

typedef __hip_bfloat16 bf16;
typedef __bf16 bf16x8 __attribute__((ext_vector_type(8)));
typedef float f32x4 __attribute__((ext_vector_type(4)));

static constexpr int cB = 200, cN = 384, cM = 512, cH = 128;
static constexpr int cNN  = cB * cN;     // 76800
static constexpr int cE   = 2 * cB * cM; // 204800 edges
static constexpr int cTWOM = 2 * cM;     // 1024
static constexpr int ZROW = 2 * cM + cN; // 1408
static constexpr int CROW = cM + 2 * cN; // 1280
static constexpr int ZBASE = cB * ZROW;  // 281600

__device__ __forceinline__ float b2f(bf16 x) { return __bfloat162float(x); }
__device__ __forceinline__ bf16  f2b(float x) { return __float2bfloat16(x); }

struct bf2 { bf16 x, y; };

// ---------------- normalize edge_index / numSwitches (int32 or int64 low words) ----
__global__ __launch_bounds__(256) void k_norm_idx(const int* __restrict__ ei_raw,
                                                  const int* __restrict__ nsw_raw,
                                                  int* __restrict__ ei, int* __restrict__ nsw) {
  int z = 0;
#pragma unroll
  for (int j = 1; j < 64; j += 2) z |= ei_raw[j];
  const int f = (z == 0) ? 1 : 0;
  const int i = blockIdx.x * 256 + threadIdx.x;
  if (i < 2 * cE) ei[i] = ei_raw[i << f];
  if (blockIdx.x == 0 && threadIdx.x < cB) nsw[threadIdx.x] = nsw_raw[threadIdx.x << f];
}

__global__ __launch_bounds__(256) void k_fill(float* p, float v, int count) {
  int i = blockIdx.x * 256 + threadIdx.x;
  if (i < count) p[i] = v;
}

__global__ __launch_bounds__(256) void k_deg(const int* __restrict__ ei, float* deg) {
  int e = blockIdx.x * 256 + threadIdx.x;
  if (e < cE) atomicAdd(&deg[ei[cE + e]], 1.0f);
}

__global__ __launch_bounds__(256) void k_dinv(float* deg) {
  int i = blockIdx.x * 256 + threadIdx.x;
  if (i < cNN) deg[i] = rsqrtf(deg[i]);
}

// ---------------- CSR build per batch: counts -> scan -> fill (src, nrm) ----------------
__global__ __launch_bounds__(512) void k_csr(const int* __restrict__ ei, const float* __restrict__ dinv,
                                             int* __restrict__ csr_off, int* __restrict__ csr_src,
                                             float* __restrict__ csr_nrm) {
  __shared__ int cnt[cN];
  __shared__ int base[cN];
  __shared__ int scanbuf[cN];
  const int tid = threadIdx.x;
  const int b = blockIdx.x;
  for (int i = tid; i < cN; i += 512) cnt[i] = 0;
  __syncthreads();
  for (int i = tid; i < cTWOM; i += 512) {
    const int d = ei[cE + b * cTWOM + i] - b * cN;
    atomicAdd(&cnt[d], 1);
  }
  __syncthreads();
  if (tid < cN) scanbuf[tid] = cnt[tid];
  __syncthreads();
  for (int off = 1; off < cN; off <<= 1) {
    int v = 0;
    if (tid < cN && tid >= off) v = scanbuf[tid - off];
    __syncthreads();
    if (tid < cN) scanbuf[tid] += v;
    __syncthreads();
  }
  if (tid < cN) {
    base[tid] = scanbuf[tid] - cnt[tid];
    csr_off[b * (cN + 1) + tid] = base[tid];
  }
  if (tid == 0) csr_off[b * (cN + 1) + cN] = scanbuf[cN - 1];
  if (tid < cN) cnt[tid] = 0;   // reuse as fill counters
  __syncthreads();
  for (int i = tid; i < cTWOM; i += 512) {
    const int e = b * cTWOM + i;
    const int s = ei[e];
    const int d = ei[cE + e];
    const int dl = d - b * cN;
    const int slot = base[dl] + atomicAdd(&cnt[dl], 1);
    csr_src[b * cTWOM + slot] = s;
    csr_nrm[b * cTWOM + slot] = dinv[s] * dinv[d];
  }
}

// ---------------- gather: hdst[n] = relu( sum_e h[src_e]*nrm_e + h[n]*dinv^2 ) ----------
// one wave per destination node; full-row coalesced reads; no atomics.
__global__ __launch_bounds__(256) void k_gather(const int* __restrict__ csr_off,
                                                const int* __restrict__ csr_src,
                                                const float* __restrict__ csr_nrm,
                                                const bf16* __restrict__ hsrc,
                                                const float* __restrict__ dinv,
                                                bf16* __restrict__ hdst) {
  const int wid = blockIdx.x * 4 + (threadIdx.x >> 6);   // node id in [0, cNN)
  const int lane = threadIdx.x & 63;
  const int b = wid / cN;
  const int nl = wid - b * cN;
  const int beg = csr_off[b * (cN + 1) + nl];
  const int end = csr_off[b * (cN + 1) + nl + 1];
  const int ebase = b * cTWOM;
  float a0 = 0.f, a1 = 0.f;
  for (int j = beg; j < end; ++j) {
    const int s = csr_src[ebase + j];
    const float w = csr_nrm[ebase + j];
    const unsigned u = *(const unsigned*)(hsrc + (size_t)s * cH + lane * 2);
    a0 = fmaf(__uint_as_float(u << 16), w, a0);
    a1 = fmaf(__uint_as_float(u & 0xffff0000u), w, a1);
  }
  const float dn = dinv[wid];
  const float dn2 = dn * dn;
  const unsigned us = *(const unsigned*)(hsrc + (size_t)wid * cH + lane * 2);
  a0 = fmaf(__uint_as_float(us << 16), dn2, a0);
  a1 = fmaf(__uint_as_float(us & 0xffff0000u), dn2, a1);
  bf2 pk;
  pk.x = f2b(fmaxf(a0, 0.f));
  pk.y = f2b(fmaxf(a1, 0.f));
  *(bf2*)(hdst + (size_t)wid * cH + lane * 2) = pk;
}

// ---------------- layer 1 linear: hraw = x@W1 + b1 ----------------
__global__ __launch_bounds__(256) void k_lin1(const float* __restrict__ x, const float* __restrict__ W1,
                                              const float* __restrict__ b1, bf16* __restrict__ hraw) {
  int idx = blockIdx.x * 256 + threadIdx.x;
  if (idx >= cNN * cH) return;
  int n = idx >> 7, h = idx & 127;
  hraw[idx] = f2b(x[2 * n] * W1[h] + x[2 * n + 1] * W1[cH + h] + b1[h]);
}

// ---------------- layer 2 linear: h2raw = h1@W2 + b2 ----------------
__global__ __launch_bounds__(256) void k_lin2(const bf16* __restrict__ h1, const float* __restrict__ W2,
                                              const float* __restrict__ b2v, bf16* __restrict__ h2raw) {
  __shared__ float w2s[64 * cH];
  __shared__ float ts[8][cH];
  const int tid = threadIdx.x;
  const int n0 = blockIdx.x * 8;
  for (int i = tid; i < 8 * cH; i += 256)
    ts[i >> 7][i & 127] = b2f(h1[(size_t)(n0 + (i >> 7)) * cH + (i & 127)]);
  const int hp = (tid & 63) * 2;
  const int ng = tid >> 6;
  const int e0 = ng, e1 = ng + 4;
  float a00 = 0, a01 = 0, a10 = 0, a11 = 0;
  for (int half = 0; half < 2; ++half) {
    __syncthreads();
    for (int i = tid; i < 64 * cH; i += 256) w2s[i] = W2[half * 64 * cH + i];
    __syncthreads();
    const int kb = half * 64;
#pragma unroll 8
    for (int k = 0; k < 64; ++k) {
      const float w0 = w2s[k * cH + hp];
      const float w1 = w2s[k * cH + hp + 1];
      const float t0 = ts[e0][kb + k];
      const float t1 = ts[e1][kb + k];
      a00 = fmaf(t0, w0, a00); a01 = fmaf(t0, w1, a01);
      a10 = fmaf(t1, w0, a10); a11 = fmaf(t1, w1, a11);
    }
  }
  h2raw[(size_t)(n0 + e0) * cH + hp]     = f2b(a00 + b2v[hp]);
  h2raw[(size_t)(n0 + e0) * cH + hp + 1] = f2b(a01 + b2v[hp + 1]);
  h2raw[(size_t)(n0 + e1) * cH + hp]     = f2b(a10 + b2v[hp]);
  h2raw[(size_t)(n0 + e1) * cH + hp + 1] = f2b(a11 + b2v[hp + 1]);
}

// ---------------- x_g = sum_n xg ----------------
__global__ __launch_bounds__(128) void k_xgsum(const bf16* __restrict__ xg, float* __restrict__ x_g) {
  int b = blockIdx.x, h = threadIdx.x;
  float s = 0.f;
  const bf16* p = xg + (size_t)b * cN * cH + h;
  for (int n = 0; n < cN; ++n) s += b2f(p[(size_t)n * cH]);
  x_g[b * cH + h] = s;
}

// ---------------- weight prep: transposes to bf16 + Wc2 pad to float4 ----------------
__global__ __launch_bounds__(256) void k_wt(const float* __restrict__ Ws1, const float* __restrict__ Wc1,
                                            const float* __restrict__ Wc2,
                                            bf16* __restrict__ Ws1t, bf16* __restrict__ Wc1t,
                                            float* __restrict__ Wc2p) {
  int idx = blockIdx.x * 256 + threadIdx.x;
  if (idx < 512 * 256) {
    int j = idx >> 8, k = idx & 255;
    Ws1t[idx] = f2b(Ws1[k * 512 + j]);
  }
  if (idx < 384 * 256) {
    int j = idx >> 8, k = idx & 255;
    Wc1t[idx] = f2b(Wc1[k * 384 + j]);
  }
  if (idx < 384 * 4) {
    int j = idx >> 2, o = idx & 3;
    Wc2p[idx] = (o < 3) ? Wc2[j * 3 + o] : 0.f;
  }
}

// ---------------- g_s = x_g@Ws1[256:]+bs1 ; g_c = x_g@Wc1[256:]+bc1 (exact, f32) ----------
__global__ __launch_bounds__(512) void k_gsgc(const float* __restrict__ x_g, const float* __restrict__ Ws1,
                                              const float* __restrict__ bs1, const float* __restrict__ Wc1,
                                              const float* __restrict__ bc1, float* __restrict__ g_s,
                                              float* __restrict__ g_c) {
  __shared__ float xs[cH];
  const int b = blockIdx.x, tid = threadIdx.x;
  if (tid < cH) xs[tid] = x_g[b * cH + tid];
  __syncthreads();
  {
    float acc = bs1[tid];
    for (int k = 0; k < cH; ++k) acc = fmaf(xs[k], Ws1[(2 * cH + k) * 512 + tid], acc);
    g_s[b * 512 + tid] = acc;
  }
  if (tid < 384) {
    float acc = bc1[tid];
    for (int k = 0; k < cH; ++k) acc = fmaf(xs[k], Wc1[(2 * cH + k) * 384 + tid], acc);
    g_c[b * 384 + tid] = acc;
  }
}

// ---------------- per-edge MLPs via MFMA: 64 edges/block, col-chunked epilogue ----------
__global__ __launch_bounds__(256) void k_mlp_mfma(
    const int* __restrict__ ei, const int* __restrict__ nsw, const bf16* __restrict__ xg,
    const bf16* __restrict__ Ws1t, const bf16* __restrict__ Wc1t,
    const float* __restrict__ g_s, const float* __restrict__ g_c,
    const float* __restrict__ Ws2, const float* __restrict__ bs2,
    const float* __restrict__ Wc2p, const float* __restrict__ bc2,
    float* __restrict__ gt_w, float* __restrict__ wvp_w, float* __restrict__ wvc_w,
    float* __restrict__ pfc_w, float* __restrict__ out) {
  constexpr int FS = 264;   // feat row stride (bf16)
  __shared__ __align__(16) bf16 feat[64 * FS];    // 33.8 KB
  __shared__ float gsl[512];                      // 2 KB
  __shared__ float gcl[384];                      // 1.5 KB
  __shared__ float red_s[4][64][4];               // 4 KB
  __shared__ float red_c[4][64][4];               // 4 KB

  const int tid = threadIdx.x;
  const int b = blockIdx.x >> 3;
  const int m0 = (blockIdx.x & 7) << 6;    // 64 edges per block
  const int wv = tid >> 6, ln = tid & 63;
  const int fr = ln & 15;
  const int g4 = ln >> 4;            // 0..3
  const int ak = g4 * 8;             // fragment k offset

  // ---- gather feat[e][0:256] = [xg[pn] | xg[cn]]; stage g vectors ----
  {
    const int e = tid >> 2, j = tid & 3;     // 4 threads per edge, 4 uint4 per half each
    const int m = m0 + e;
    const int pn = ei[b * cTWOM + m];
    const int cn = ei[b * cTWOM + cM + m];
    const uint4* ps = (const uint4*)(xg + (size_t)pn * cH);
    const uint4* cs = (const uint4*)(xg + (size_t)cn * cH);
    uint4* fp = (uint4*)(feat + e * FS);
    uint4* fc = (uint4*)(feat + e * FS + 128);
#pragma unroll
    for (int r = 0; r < 4; ++r) {
      fp[j * 4 + r] = ps[j * 4 + r];
      fc[j * 4 + r] = cs[j * 4 + r];
    }
  }
  for (int i = tid; i < 512; i += 256) gsl[i] = g_s[b * 512 + i];
  for (int i = tid; i < 384; i += 256) gcl[i] = g_c[b * 384 + i];
  __syncthreads();

  const bf16* ap = feat + fr * FS + ak;

  // ================= S path: wave cols [wv*128, wv*128+128), 2 chunks x 4 nt ==========
  {
    float p[4][4][4];   // [m][i][o]
#pragma unroll
    for (int m = 0; m < 4; ++m)
#pragma unroll
      for (int i = 0; i < 4; ++i)
#pragma unroll
        for (int o = 0; o < 4; ++o) p[m][i][o] = 0.f;
    const bf16* bp = Ws1t + ((size_t)(wv * 128 + fr)) * 256 + ak;
#pragma unroll
    for (int c = 0; c < 2; ++c) {
      f32x4 acc[4][4];
#pragma unroll
      for (int m = 0; m < 4; ++m)
#pragma unroll
        for (int j = 0; j < 4; ++j) acc[m][j] = f32x4{0.f, 0.f, 0.f, 0.f};
      const bf16* bpc = bp + (size_t)(c * 4) * 16 * 256;
#pragma unroll
      for (int kt = 0; kt < 8; ++kt) {
        const int ko = kt * 32;
        const bf16x8 a0 = *(const bf16x8*)(ap + ko);
        const bf16x8 a1 = *(const bf16x8*)(ap + 16 * FS + ko);
        const bf16x8 a2 = *(const bf16x8*)(ap + 32 * FS + ko);
        const bf16x8 a3 = *(const bf16x8*)(ap + 48 * FS + ko);
#pragma unroll
        for (int j = 0; j < 4; ++j) {
          const bf16x8 bfr = *(const bf16x8*)(bpc + (size_t)j * 16 * 256 + ko);
          acc[0][j] = __builtin_amdgcn_mfma_f32_16x16x32_bf16(a0, bfr, acc[0][j], 0, 0, 0);
          acc[1][j] = __builtin_amdgcn_mfma_f32_16x16x32_bf16(a1, bfr, acc[1][j], 0, 0, 0);
          acc[2][j] = __builtin_amdgcn_mfma_f32_16x16x32_bf16(a2, bfr, acc[2][j], 0, 0, 0);
          acc[3][j] = __builtin_amdgcn_mfma_f32_16x16x32_bf16(a3, bfr, acc[3][j], 0, 0, 0);
        }
      }
      // fold chunk into p (relu + g, second layer)
#pragma unroll
      for (int j = 0; j < 4; ++j) {
        const int col = wv * 128 + (c * 4 + j) * 16 + fr;
        const float4 w4 = *(const float4*)(Ws2 + col * 4);
        const float gs = gsl[col];
#pragma unroll
        for (int m = 0; m < 4; ++m)
#pragma unroll
          for (int i = 0; i < 4; ++i) {
            const float hv = fmaxf(acc[m][j][i] + gs, 0.f);
            p[m][i][0] = fmaf(hv, w4.x, p[m][i][0]);
            p[m][i][1] = fmaf(hv, w4.y, p[m][i][1]);
            p[m][i][2] = fmaf(hv, w4.z, p[m][i][2]);
            p[m][i][3] = fmaf(hv, w4.w, p[m][i][3]);
          }
      }
    }
#pragma unroll
    for (int mask = 1; mask <= 8; mask <<= 1)
#pragma unroll
      for (int m = 0; m < 4; ++m)
#pragma unroll
        for (int i = 0; i < 4; ++i)
#pragma unroll
          for (int o = 0; o < 4; ++o) p[m][i][o] += __shfl_xor(p[m][i][o], mask);
    if (fr == 0) {
#pragma unroll
      for (int m = 0; m < 4; ++m)
#pragma unroll
        for (int i = 0; i < 4; ++i) {
          const int row = m * 16 + g4 * 4 + i;
#pragma unroll
          for (int o = 0; o < 4; ++o) red_s[wv][row][o] = p[m][i][o];
        }
    }
  }

  // ================= C path: wave cols [wv*96, wv*96+96), 2 chunks x 3 nt ============
  {
    float p[4][4][4];
#pragma unroll
    for (int m = 0; m < 4; ++m)
#pragma unroll
      for (int i = 0; i < 4; ++i)
#pragma unroll
        for (int o = 0; o < 4; ++o) p[m][i][o] = 0.f;
    const bf16* bp = Wc1t + ((size_t)(wv * 96 + fr)) * 256 + ak;
#pragma unroll
    for (int c = 0; c < 2; ++c) {
      f32x4 acc[4][3];
#pragma unroll
      for (int m = 0; m < 4; ++m)
#pragma unroll
        for (int j = 0; j < 3; ++j) acc[m][j] = f32x4{0.f, 0.f, 0.f, 0.f};
      const bf16* bpc = bp + (size_t)(c * 3) * 16 * 256;
#pragma unroll
      for (int kt = 0; kt < 8; ++kt) {
        const int ko = kt * 32;
        const bf16x8 a0 = *(const bf16x8*)(ap + ko);
        const bf16x8 a1 = *(const bf16x8*)(ap + 16 * FS + ko);
        const bf16x8 a2 = *(const bf16x8*)(ap + 32 * FS + ko);
        const bf16x8 a3 = *(const bf16x8*)(ap + 48 * FS + ko);
#pragma unroll
        for (int j = 0; j < 3; ++j) {
          const bf16x8 bfr = *(const bf16x8*)(bpc + (size_t)j * 16 * 256 + ko);
          acc[0][j] = __builtin_amdgcn_mfma_f32_16x16x32_bf16(a0, bfr, acc[0][j], 0, 0, 0);
          acc[1][j] = __builtin_amdgcn_mfma_f32_16x16x32_bf16(a1, bfr, acc[1][j], 0, 0, 0);
          acc[2][j] = __builtin_amdgcn_mfma_f32_16x16x32_bf16(a2, bfr, acc[2][j], 0, 0, 0);
          acc[3][j] = __builtin_amdgcn_mfma_f32_16x16x32_bf16(a3, bfr, acc[3][j], 0, 0, 0);
        }
      }
#pragma unroll
      for (int j = 0; j < 3; ++j) {
        const int col = wv * 96 + (c * 3 + j) * 16 + fr;
        const float4 w4 = *(const float4*)(Wc2p + col * 4);
        const float gc = gcl[col];
#pragma unroll
        for (int m = 0; m < 4; ++m)
#pragma unroll
          for (int i = 0; i < 4; ++i) {
            const float hv = fmaxf(acc[m][j][i] + gc, 0.f);
            p[m][i][0] = fmaf(hv, w4.x, p[m][i][0]);
            p[m][i][1] = fmaf(hv, w4.y, p[m][i][1]);
            p[m][i][2] = fmaf(hv, w4.z, p[m][i][2]);
          }
      }
    }
#pragma unroll
    for (int mask = 1; mask <= 8; mask <<= 1)
#pragma unroll
      for (int m = 0; m < 4; ++m)
#pragma unroll
        for (int i = 0; i < 4; ++i)
#pragma unroll
          for (int o = 0; o < 3; ++o) p[m][i][o] += __shfl_xor(p[m][i][o], mask);
    if (fr == 0) {
#pragma unroll
      for (int m = 0; m < 4; ++m)
#pragma unroll
        for (int i = 0; i < 4; ++i) {
          const int row = m * 16 + g4 * 4 + i;
#pragma unroll
          for (int o = 0; o < 3; ++o) red_c[wv][row][o] = p[m][i][o];
        }
    }
  }
  __syncthreads();

  // ---- combine / mask / outputs ----
  if (tid < 64) {
    const int e = tid, m = m0 + e;
    const int ns = nsw[b];
    const bool mk = (m >= cM - ns);
    const float s0  = red_s[0][e][0] + red_s[1][e][0] + red_s[2][e][0] + red_s[3][e][0] + bs2[0];
    const float sv1 = red_s[0][e][1] + red_s[1][e][1] + red_s[2][e][1] + red_s[3][e][1] + bs2[1];
    const float sv2 = red_s[0][e][2] + red_s[1][e][2] + red_s[2][e][2] + red_s[3][e][2] + bs2[2];
    const float sv3 = red_s[0][e][3] + red_s[1][e][3] + red_s[2][e][3] + red_s[3][e][3] + bs2[3];
    const float c0  = red_c[0][e][0] + red_c[1][e][0] + red_c[2][e][0] + red_c[3][e][0] + bc2[0];
    const float c1  = red_c[0][e][1] + red_c[1][e][1] + red_c[2][e][1] + red_c[3][e][1] + bc2[1];
    const float c2  = red_c[0][e][2] + red_c[1][e][2] + red_c[2][e][2] + red_c[3][e][2] + bc2[2];
    const float gt = mk ? (1.f / (1.f + expf(-s0))) : 1.f;
    const float pf = mk ? sv1 : c0;
    const float vp = mk ? sv2 : c1;
    const float vc = mk ? sv3 : c2;
    const float pfc = pf * gt;
    const int bm = b * cM + m;
    gt_w[bm] = gt; wvp_w[bm] = vp; wvc_w[bm] = vc; pfc_w[bm] = pfc;
    out[b * ZROW + m] = pfc;
    out[b * ZROW + cM + cN + m] = gt;
  }
}

// ---------------- v einsums ----------------
__global__ __launch_bounds__(256) void k_v(const float* __restrict__ incP, const float* __restrict__ incC,
                                           const float* __restrict__ wvp, const float* __restrict__ wvc,
                                           const float* __restrict__ invdeg, float* __restrict__ v_w,
                                           float* __restrict__ out) {
  const int wid = blockIdx.x * 4 + (threadIdx.x >> 6);
  const int lane = threadIdx.x & 63;
  const int b = wid / cN, n = wid % cN;
  const size_t rowoff = (size_t)(b * cN + n) * cM + lane * 8;
  const float4 p0 = *(const float4*)(incP + rowoff);
  const float4 p1 = *(const float4*)(incP + rowoff + 4);
  const float4 c0 = *(const float4*)(incC + rowoff);
  const float4 c1 = *(const float4*)(incC + rowoff + 4);
  const float* wp = wvp + b * cM + lane * 8;
  const float* wc = wvc + b * cM + lane * 8;
  float s;
  s = p0.x * wp[0] + p0.y * wp[1] + p0.z * wp[2] + p0.w * wp[3] +
      p1.x * wp[4] + p1.y * wp[5] + p1.z * wp[6] + p1.w * wp[7];
  s += c0.x * wc[0] + c0.y * wc[1] + c0.z * wc[2] + c0.w * wc[3] +
       c1.x * wc[4] + c1.y * wc[5] + c1.z * wc[6] + c1.w * wc[7];
#pragma unroll
  for (int off = 32; off >= 1; off >>= 1) s += __shfl_down(s, off);
  if (lane == 0) {
    float val = invdeg[b * cN + n] * s;
    if (n == 0) val = 1.0f;
    v_w[b * cN + n] = val;
    out[b * ZROW + cM + n] = val;
  }
}

// ---------------- q_fc = (A^T v) * graph_topo ----------------
__global__ __launch_bounds__(256) void k_qfc(const float* __restrict__ A, const float* __restrict__ v_w,
                                             const float* __restrict__ gt_w, float* __restrict__ qfc_w,
                                             float* __restrict__ out) {
  __shared__ float vs[cN];
  const int b = blockIdx.x >> 1;
  const int m = ((blockIdx.x & 1) << 8) + threadIdx.x;
  for (int i = threadIdx.x; i < cN; i += 256) vs[i] = v_w[b * cN + i];
  __syncthreads();
  float s = 0.f;
  for (int n = 0; n < cN; ++n) s = fmaf(A[n * cM + m], vs[n], s);
  const int bm = b * cM + m;
  const float q = s * gt_w[bm];
  qfc_w[bm] = q;
  out[ZBASE + b * CROW + m] = q;
}

// ---------------- pg / qg ----------------
__global__ __launch_bounds__(256) void k_pgqg(const float* __restrict__ A, const float* __restrict__ x,
                                              const float* __restrict__ pfc, const float* __restrict__ qfc,
                                              float* __restrict__ out) {
  const int idx = blockIdx.x * 256 + threadIdx.x;
  if (idx >= cNN) return;
  const int b = idx / cN, n = idx % cN;
  const float* ar = A + (size_t)n * cM;
  const float* pf = pfc + b * cM;
  const float* qf = qfc + b * cM;
  float ps = 0.f, qs = 0.f;
  for (int mm = 0; mm < cM; mm += 4) {
    const float4 ua = *(const float4*)(ar + mm);
    ps += ua.x * pf[mm] + ua.y * pf[mm + 1] + ua.z * pf[mm + 2] + ua.w * pf[mm + 3];
    qs += ua.x * qf[mm] + ua.y * qf[mm + 1] + ua.z * qf[mm + 2] + ua.w * qf[mm + 3];
  }
  out[ZBASE + b * CROW + cM + n] = x[2 * idx] + ps;
  out[ZBASE + b * CROW + cM + cN + n] = x[2 * idx + 1] + qs;
}

extern "C" void kernel_launch(void* const* d_in, const int* in_sizes, int n_in,
                              void* d_out, int out_size, void* d_ws, size_t ws_size,
                              hipStream_t stream) {
  const bool dict_order = (in_sizes[1] == 2 * cE);
  int IEI, INSW, IIVD, IIP, IIC, IA, IW;
  if (dict_order) { IEI = 1; INSW = 2; IIVD = 3; IIP = 4; IIC = 5; IA = 6; IW = 7; }
  else            { IIVD = 1; IIP = 2; IIC = 3; IA = 4; IW = 5; IEI = 17; INSW = 18; }

  const float* x = (const float*)d_in[0];
  const int* ei_raw = (const int*)d_in[IEI];
  const int* nsw_raw = (const int*)d_in[INSW];
  const float* invdeg = (const float*)d_in[IIVD];
  const float* incP = (const float*)d_in[IIP];
  const float* incC = (const float*)d_in[IIC];
  const float* A = (const float*)d_in[IA];
  const float* W1 = (const float*)d_in[IW + 0];
  const float* b1 = (const float*)d_in[IW + 1];
  const float* W2 = (const float*)d_in[IW + 2];
  const float* b2 = (const float*)d_in[IW + 3];
  const float* Ws1 = (const float*)d_in[IW + 4];
  const float* bs1 = (const float*)d_in[IW + 5];
  const float* Ws2 = (const float*)d_in[IW + 6];
  const float* bs2 = (const float*)d_in[IW + 7];
  const float* Wc1 = (const float*)d_in[IW + 8];
  const float* bc1 = (const float*)d_in[IW + 9];
  const float* Wc2 = (const float*)d_in[IW + 10];
  const float* bc2 = (const float*)d_in[IW + 11];
  float* out = (float*)d_out;

  // ---- workspace (~47 MB; well under proven 83.6 MB) ----
  char* w = (char*)d_ws;
  auto alloc = [&](size_t bytes) { void* p = (void*)w; w += (bytes + 255) & ~(size_t)255; return p; };
  float* dinv = (float*)alloc((size_t)cNN * 4);
  int* ei = (int*)alloc((size_t)2 * cE * 4);
  int* nsw = (int*)alloc((size_t)cB * 4);
  bf16* hbufA = (bf16*)alloc((size_t)cNN * cH * 2);  // hraw1 -> h2raw
  bf16* hbufB = (bf16*)alloc((size_t)cNN * cH * 2);  // h1 -> xg
  int* csr_off = (int*)alloc((size_t)cB * (cN + 1) * 4);
  int* csr_src = (int*)alloc((size_t)cE * 4);
  float* csr_nrm = (float*)alloc((size_t)cE * 4);
  bf16* Ws1t = (bf16*)alloc((size_t)512 * 256 * 2);
  bf16* Wc1t = (bf16*)alloc((size_t)384 * 256 * 2);
  float* g_s = (float*)alloc((size_t)cB * 512 * 4);
  float* g_c = (float*)alloc((size_t)cB * 384 * 4);
  float* Wc2p = (float*)alloc((size_t)384 * 4 * 4);
  float* x_g = (float*)alloc((size_t)cB * cH * 4);
  float* gt_w = (float*)alloc((size_t)cB * cM * 4);
  float* wvp_w = (float*)alloc((size_t)cB * cM * 4);
  float* wvc_w = (float*)alloc((size_t)cB * cM * 4);
  float* pfc_w = (float*)alloc((size_t)cB * cM * 4);
  float* qfc_w = (float*)alloc((size_t)cB * cM * 4);
  float* v_w = (float*)alloc((size_t)cB * cN * 4);

  const int NH = cNN * cH;
  k_norm_idx<<<(2 * cE) / 256, 256, 0, stream>>>(ei_raw, nsw_raw, ei, nsw);
  k_fill<<<(cNN + 255) / 256, 256, 0, stream>>>(dinv, 1.0f, cNN);
  k_deg<<<cE / 256, 256, 0, stream>>>(ei, dinv);
  k_dinv<<<(cNN + 255) / 256, 256, 0, stream>>>(dinv);
  k_csr<<<cB, 512, 0, stream>>>(ei, dinv, csr_off, csr_src, csr_nrm);

  // GCN layer 1: lin1 -> A; gather A -> B (h1)
  k_lin1<<<NH / 256, 256, 0, stream>>>(x, W1, b1, hbufA);
  k_gather<<<cNN / 4, 256, 0, stream>>>(csr_off, csr_src, csr_nrm, hbufA, dinv, hbufB);

  // GCN layer 2: lin2 B -> A (h2raw); gather A -> B (xg)
  k_lin2<<<cNN / 8, 256, 0, stream>>>(hbufB, W2, b2, hbufA);
  k_gather<<<cNN / 4, 256, 0, stream>>>(csr_off, csr_src, csr_nrm, hbufA, dinv, hbufB);

  bf16* xg = hbufB;
  k_wt<<<512, 256, 0, stream>>>(Ws1, Wc1, Wc2, Ws1t, Wc1t, Wc2p);
  k_xgsum<<<cB, 128, 0, stream>>>(xg, x_g);
  k_gsgc<<<cB, 512, 0, stream>>>(x_g, Ws1, bs1, Wc1, bc1, g_s, g_c);

  // per-edge MLPs on matrix cores (64 edges/block)
  k_mlp_mfma<<<cB * 8, 256, 0, stream>>>(ei, nsw, xg, Ws1t, Wc1t, g_s, g_c,
                                         Ws2, bs2, Wc2p, bc2,
                                         gt_w, wvp_w, wvc_w, pfc_w, out);

  k_v<<<cB * cN / 4, 256, 0, stream>>>(incP, incC, wvp_w, wvc_w, invdeg, v_w, out);
  k_qfc<<<cB * cM / 256, 256, 0, stream>>>(A, v_w, gt_w, qfc_w, out);
  k_pgqg<<<(cNN + 255) / 256, 256, 0, stream>>>(A, x, pfc_w, qfc_w, out);
}